// Round 1
// baseline (645.471 us; speedup 1.0000x reference)
//
#include <hip/hip_runtime.h>

#define D 128
#define EDIM 64
#define TDIM 64
#define KTOT 256
#define CHUNK 32
#define NCH 8
#define NP 5
#define LN_EPS 1e-4f

__device__ __forceinline__ float clipf(float x, float lo, float hi) {
    return fminf(fmaxf(x, lo), hi);
}

// ---------------- K0: fold weights into ws ----------------
// ws layout (floats): Wt[256*128] (k-major: Wt[k][d]), c0[128], cc[3]={sgg,sgb,sbb}
__global__ void k0_fold(const float* __restrict__ qw, const float* __restrict__ qb,
                        const float* __restrict__ ew, const float* __restrict__ eb,
                        const float* __restrict__ pg, const float* __restrict__ pb,
                        float* __restrict__ ws) {
    const int d = threadIdx.x;   // 0..127
    const int bk = blockIdx.x;   // 0..257
    float* Wt = ws;
    float* c0 = ws + KTOT * D;
    float* cc = c0 + D;
    if (bk < 128) {
        Wt[bk * D + d] = qw[d * 320 + bk];
    } else if (bk < 192) {
        const int e = bk - 128;
        const float4* qrow = (const float4*)(qw + d * 320 + 128);
        float s = 0.f;
        #pragma unroll
        for (int g = 0; g < 32; ++g) {
            float4 q = qrow[g];
            s = fmaf(q.x, ew[(4 * g + 0) * EDIM + e], s);
            s = fmaf(q.y, ew[(4 * g + 1) * EDIM + e], s);
            s = fmaf(q.z, ew[(4 * g + 2) * EDIM + e], s);
            s = fmaf(q.w, ew[(4 * g + 3) * EDIM + e], s);
        }
        Wt[bk * D + d] = s;
    } else if (bk < 256) {
        Wt[bk * D + d] = qw[d * 320 + 256 + (bk - 192)];
    } else if (bk == 256) {
        const float4* qrow = (const float4*)(qw + d * 320 + 128);
        const float4* eb4 = (const float4*)eb;
        float s = qb[d];
        #pragma unroll
        for (int g = 0; g < 32; ++g) {
            float4 q = qrow[g], e4 = eb4[g];
            s = fmaf(q.x, e4.x, s); s = fmaf(q.y, e4.y, s);
            s = fmaf(q.z, e4.z, s); s = fmaf(q.w, e4.w, s);
        }
        c0[d] = s;
    } else {
        if (d == 0) { float s = 0.f; for (int i = 0; i < D; ++i) s = fmaf(pg[i], pg[i], s); cc[0] = s; }
        if (d == 1) { float s = 0.f; for (int i = 0; i < D; ++i) s = fmaf(pg[i], pb[i], s); cc[1] = s; }
        if (d == 2) { float s = 0.f; for (int i = 0; i < D; ++i) s = fmaf(pb[i], pb[i], s); cc[2] = s; }
    }
}

// ---------------- K1: fused main kernel, one lane per batch element ----------------
__global__ __launch_bounds__(256, 2)
void k1_main(const int* __restrict__ nids, const float* __restrict__ ef,
             const float* __restrict__ tarr, const float* __restrict__ raw_mem,
             const float* __restrict__ protos,
             const float* __restrict__ pg, const float* __restrict__ pb,
             const float* __restrict__ tw, const float* __restrict__ tb,
             const float* __restrict__ cg, const float* __restrict__ cb,
             const float* __restrict__ gw, const float* __restrict__ gb,
             const float* __restrict__ temp, const float* __restrict__ ws,
             float* __restrict__ out, int Btot) {
    __shared__ float Wbuf[CHUNK * D];    // 16KB; reused after GEMM as mubuf/rsbuf/smbuf [5][256] each
    __shared__ float vbuf[CHUNK * 256];  // 32KB, layout [k][tid]
    __shared__ float2 pgb2[D];
    __shared__ float2 u12[D];            // {g*g, g*b}
    __shared__ float2 cgb2[D];
    __shared__ float gwb[2 * D + TDIM];  // 320
    __shared__ float2 ttb[TDIM];

    const int tid = threadIdx.x;
    int b = blockIdx.x * 256 + tid;
    const bool active = (b < Btot);
    if (b >= Btot) b = Btot - 1;

    if (tid < D) {
        float g = pg[tid], bb = pb[tid];
        pgb2[tid] = make_float2(g, bb);
        u12[tid] = make_float2(g * g, g * bb);
        cgb2[tid] = make_float2(cg[tid], cb[tid]);
    }
    if (tid < TDIM) ttb[tid] = make_float2(tw[tid], tb[tid]);
    gwb[tid] = gw[tid];
    if (tid < 2 * D + TDIM - 256) gwb[tid + 256] = gw[tid + 256];

    const int nid = nids[b];
    const float tval = tarr[b];
    const float* c0 = ws + KTOT * D;
    const float* cc = c0 + D;
    const float sgg = cc[0], sgb = cc[1], sbb = cc[2];
    const float tempc = fminf(fmaxf(temp[0], 0.05f), 2.0f) + 1e-4f;
    const float its = 1.0f / tempc;
    const float gateb = gb[0];

    const float* rawrow = raw_mem + (size_t)nid * D;

    // init acc with folded bias c0
    float vec[D];
    {
        const float4* c04 = (const float4*)c0;
        #pragma unroll
        for (int g = 0; g < D / 4; ++g) {
            float4 v4 = c04[g];
            vec[4 * g] = v4.x; vec[4 * g + 1] = v4.y; vec[4 * g + 2] = v4.z; vec[4 * g + 3] = v4.w;
        }
    }

    float graw = 0.f, gte = 0.f;

    // ---- GEMM phase: q_pre = W' @ [raw, ef, te] + c0 ----
    for (int c = 0; c < NCH; ++c) {
        __syncthreads();
        {   // stage W chunk (coalesced)
            const float4* wsrc = (const float4*)(ws + c * CHUNK * D);
            float4* wdst = (float4*)Wbuf;
            #pragma unroll
            for (int r = 0; r < 4; ++r) wdst[r * 256 + tid] = wsrc[r * 256 + tid];
        }
        if (c < 4) {            // raw part, k in [0,128)
            const float4* rsrc = (const float4*)(rawrow + c * CHUNK);
            #pragma unroll
            for (int g = 0; g < 8; ++g) {
                float4 x = rsrc[g];
                const int k0 = 4 * g;
                vbuf[(k0 + 0) * 256 + tid] = x.x;
                vbuf[(k0 + 1) * 256 + tid] = x.y;
                vbuf[(k0 + 2) * 256 + tid] = x.z;
                vbuf[(k0 + 3) * 256 + tid] = x.w;
                const int gi0 = c * CHUNK + k0;
                graw = fmaf(gwb[gi0 + 0], clipf(x.x, -100.f, 100.f), graw);
                graw = fmaf(gwb[gi0 + 1], clipf(x.y, -100.f, 100.f), graw);
                graw = fmaf(gwb[gi0 + 2], clipf(x.z, -100.f, 100.f), graw);
                graw = fmaf(gwb[gi0 + 3], clipf(x.w, -100.f, 100.f), graw);
            }
        } else if (c < 6) {     // edge features, k in [128,192)
            const float4* esrc = (const float4*)(ef + (size_t)b * EDIM + (c - 4) * CHUNK);
            #pragma unroll
            for (int g = 0; g < 8; ++g) {
                float4 x = esrc[g];
                const int k0 = 4 * g;
                vbuf[(k0 + 0) * 256 + tid] = x.x;
                vbuf[(k0 + 1) * 256 + tid] = x.y;
                vbuf[(k0 + 2) * 256 + tid] = x.z;
                vbuf[(k0 + 3) * 256 + tid] = x.w;
            }
        } else {                // time encoding, k in [192,256)
            #pragma unroll
            for (int j = 0; j < CHUNK; ++j) {
                const int u = (c - 6) * CHUNK + j;
                float2 wt2 = ttb[u];
                float te = __cosf(fmaf(tval, wt2.x, wt2.y));
                gte = fmaf(gwb[2 * D + u], te, gte);
                vbuf[j * 256 + tid] = te;
            }
        }
        __syncthreads();
        #pragma unroll 1
        for (int k = 0; k < CHUNK; ++k) {
            const float vk = vbuf[k * 256 + tid];
            const float4* wrow = (const float4*)(Wbuf + k * D);
            #pragma unroll
            for (int dq = 0; dq < D / 4; ++dq) {
                float4 w = wrow[dq];
                vec[4 * dq]     = fmaf(vk, w.x, vec[4 * dq]);
                vec[4 * dq + 1] = fmaf(vk, w.y, vec[4 * dq + 1]);
                vec[4 * dq + 2] = fmaf(vk, w.z, vec[4 * dq + 2]);
                vec[4 * dq + 3] = fmaf(vk, w.w, vec[4 * dq + 3]);
            }
        }
    }
    __syncthreads();  // Wbuf reused below

    // ---- query = tanh(LN(q_pre)); qn; vec <- qn*g ----
    float s0 = 0.f, s1 = 0.f, s2 = 0.f, s3 = 0.f;
    #pragma unroll
    for (int d = 0; d < D; d += 4) { s0 += vec[d]; s1 += vec[d + 1]; s2 += vec[d + 2]; s3 += vec[d + 3]; }
    const float mu = (s0 + s1 + s2 + s3) * (1.f / D);
    s0 = s1 = s2 = s3 = 0.f;
    #pragma unroll
    for (int d = 0; d < D; d += 4) {
        float a = vec[d] - mu, b2 = vec[d + 1] - mu, c2 = vec[d + 2] - mu, e2 = vec[d + 3] - mu;
        s0 = fmaf(a, a, s0); s1 = fmaf(b2, b2, s1); s2 = fmaf(c2, c2, s2); s3 = fmaf(e2, e2, s3);
    }
    const float var = (s0 + s1 + s2 + s3) * (1.f / D);
    const float rsq = __builtin_amdgcn_rsqf(var + LN_EPS);
    float ssq = 0.f;
    #pragma unroll
    for (int d = 0; d < D; ++d) {
        float2 gbv = cgb2[d];
        float x = fmaf((vec[d] - mu) * rsq, gbv.x, gbv.y);
        float e2x = __expf(2.f * x);
        float th = 1.f - 2.f * __builtin_amdgcn_rcpf(e2x + 1.f);
        vec[d] = th;
        ssq = fmaf(th, th, ssq);
    }
    const float nq = sqrtf(ssq);
    const float invq = __builtin_amdgcn_rcpf(fmaxf(nq, 1e-6f));
    float aqg = 0.f, aqb = 0.f;
    #pragma unroll
    for (int d = 0; d < D; ++d) {
        float2 gbv = pgb2[d];
        float qn = vec[d] * invq;
        float qg = qn * gbv.x;
        aqg += qg;
        aqb = fmaf(qn, gbv.y, aqb);
        vec[d] = qg;  // vec now holds qn*g
    }

    // ---- pass 1 over prototypes: LN stats + cosine sim in one stream ----
    float* mubuf = Wbuf;
    float* rsbuf = Wbuf + 5 * 256;
    float* smbuf = Wbuf + 10 * 256;
    const float* prow0 = protos + (size_t)nid * NP * D;
    #pragma unroll 1
    for (int p = 0; p < NP; ++p) {
        const float4* xr = (const float4*)(prow0 + p * D);
        float sx = 0.f, sxx = 0.f, sgx2 = 0.f, sgx = 0.f, sgbx = 0.f, sqgx = 0.f;
        #pragma unroll
        for (int g = 0; g < D / 4; ++g) {
            float4 x4 = xr[g];
            {
                const int d = 4 * g; float x = x4.x; float2 u = u12[d]; float xx = x * x;
                sx += x; sxx = fmaf(x, x, sxx); sgx2 = fmaf(u.x, xx, sgx2);
                sgx = fmaf(u.x, x, sgx); sgbx = fmaf(u.y, x, sgbx); sqgx = fmaf(vec[d], x, sqgx);
            }
            {
                const int d = 4 * g + 1; float x = x4.y; float2 u = u12[d]; float xx = x * x;
                sx += x; sxx = fmaf(x, x, sxx); sgx2 = fmaf(u.x, xx, sgx2);
                sgx = fmaf(u.x, x, sgx); sgbx = fmaf(u.y, x, sgbx); sqgx = fmaf(vec[d], x, sqgx);
            }
            {
                const int d = 4 * g + 2; float x = x4.z; float2 u = u12[d]; float xx = x * x;
                sx += x; sxx = fmaf(x, x, sxx); sgx2 = fmaf(u.x, xx, sgx2);
                sgx = fmaf(u.x, x, sgx); sgbx = fmaf(u.y, x, sgbx); sqgx = fmaf(vec[d], x, sqgx);
            }
            {
                const int d = 4 * g + 3; float x = x4.w; float2 u = u12[d]; float xx = x * x;
                sx += x; sxx = fmaf(x, x, sxx); sgx2 = fmaf(u.x, xx, sgx2);
                sgx = fmaf(u.x, x, sgx); sgbx = fmaf(u.y, x, sgbx); sqgx = fmaf(vec[d], x, sqgx);
            }
        }
        const float mup = sx * (1.f / D);
        const float varp = sxx * (1.f / D) - mup * mup;
        const float rsp = __builtin_amdgcn_rsqf(varp + LN_EPS);
        const float dot = fmaf(rsp, sqgx - mup * aqg, aqb);
        float nrm2 = rsp * rsp * (sgx2 - 2.f * mup * sgx + mup * mup * sgg)
                   + 2.f * rsp * (sgbx - mup * sgb) + sbb;
        nrm2 = fmaxf(nrm2, 0.f);
        const float nr = sqrtf(nrm2);
        const float inv = __builtin_amdgcn_rcpf(fmaxf(nr, 1e-6f));
        const float sim = clipf(dot * inv, -30.f, 30.f) * its;
        mubuf[p * 256 + tid] = mup;
        rsbuf[p * 256 + tid] = rsp;
        smbuf[p * 256 + tid] = sim;
    }

    // ---- softmax over 5 prototypes ----
    float sims[NP];
    #pragma unroll
    for (int p = 0; p < NP; ++p) sims[p] = smbuf[p * 256 + tid];
    float mx = fmaxf(fmaxf(fmaxf(sims[0], sims[1]), fmaxf(sims[2], sims[3])), sims[4]);
    float Z = 0.f;
    #pragma unroll
    for (int p = 0; p < NP; ++p) { sims[p] = __expf(sims[p] - mx); Z += sims[p]; }
    const float iZ = 1.f / Z;
    float a0 = 0.f, a1 = 0.f;
    #pragma unroll
    for (int p = 0; p < NP; ++p) {
        float at = sims[p] * iZ;
        a0 += at;
        float wp = at * rsbuf[p * 256 + tid];
        a1 = fmaf(wp, mubuf[p * 256 + tid], a1);
        smbuf[p * 256 + tid] = wp;  // store weight attn*rs
    }

    // ---- pass 3: S[d] = sum_p wp * x_pd ----
    #pragma unroll
    for (int d = 0; d < D; ++d) vec[d] = 0.f;
    #pragma unroll 1
    for (int p = 0; p < NP; ++p) {
        const float wp = smbuf[p * 256 + tid];
        const float4* xr = (const float4*)(prow0 + p * D);
        #pragma unroll
        for (int g = 0; g < D / 4; ++g) {
            float4 x4 = xr[g];
            vec[4 * g]     = fmaf(wp, x4.x, vec[4 * g]);
            vec[4 * g + 1] = fmaf(wp, x4.y, vec[4 * g + 1]);
            vec[4 * g + 2] = fmaf(wp, x4.z, vec[4 * g + 2]);
            vec[4 * g + 3] = fmaf(wp, x4.w, vec[4 * g + 3]);
        }
    }

    // ---- cand + gate ----
    float gcand = 0.f;
    #pragma unroll
    for (int d = 0; d < D; ++d) {
        float2 gbv = pgb2[d];
        float cnd = clipf(fmaf(gbv.x, vec[d] - a1, gbv.y * a0), -5.f, 5.f);
        gcand = fmaf(gwb[D + d], cnd, gcand);
        vec[d] = cnd;
    }
    const float gpre = graw + gcand + gte + gateb;
    const float gate = __builtin_amdgcn_rcpf(1.f + __expf(-gpre));

    // ---- upd = raw + gate*(cand-raw); LN; clip; store ----
    float su = 0.f, ssu = 0.f;
    {
        const float4* rr = (const float4*)rawrow;
        #pragma unroll
        for (int g = 0; g < D / 4; ++g) {
            float4 r4 = rr[g];
            {
                const int d = 4 * g;
                float u = fmaf(gate, vec[d] - r4.x, r4.x); vec[d] = u; su += u; ssu = fmaf(u, u, ssu);
            }
            {
                const int d = 4 * g + 1;
                float u = fmaf(gate, vec[d] - r4.y, r4.y); vec[d] = u; su += u; ssu = fmaf(u, u, ssu);
            }
            {
                const int d = 4 * g + 2;
                float u = fmaf(gate, vec[d] - r4.z, r4.z); vec[d] = u; su += u; ssu = fmaf(u, u, ssu);
            }
            {
                const int d = 4 * g + 3;
                float u = fmaf(gate, vec[d] - r4.w, r4.w); vec[d] = u; su += u; ssu = fmaf(u, u, ssu);
            }
        }
    }
    const float muu = su * (1.f / D);
    const float varu = ssu * (1.f / D) - muu * muu;
    const float rsu = __builtin_amdgcn_rsqf(varu + LN_EPS);

    if (active) {
        float4* orow = (float4*)(out + (size_t)b * D);
        #pragma unroll
        for (int g = 0; g < D / 4; ++g) {
            float4 o;
            {
                const int d = 4 * g;     float2 gbv = cgb2[d];
                o.x = clipf(fmaf((vec[d] - muu) * rsu, gbv.x, gbv.y), -10.f, 10.f);
            }
            {
                const int d = 4 * g + 1; float2 gbv = cgb2[d];
                o.y = clipf(fmaf((vec[d] - muu) * rsu, gbv.x, gbv.y), -10.f, 10.f);
            }
            {
                const int d = 4 * g + 2; float2 gbv = cgb2[d];
                o.z = clipf(fmaf((vec[d] - muu) * rsu, gbv.x, gbv.y), -10.f, 10.f);
            }
            {
                const int d = 4 * g + 3; float2 gbv = cgb2[d];
                o.w = clipf(fmaf((vec[d] - muu) * rsu, gbv.x, gbv.y), -10.f, 10.f);
            }
            orow[g] = o;
        }
    }
}

extern "C" void kernel_launch(void* const* d_in, const int* in_sizes, int n_in,
                              void* d_out, int out_size, void* d_ws, size_t ws_size,
                              hipStream_t stream) {
    const int*   nids = (const int*)d_in[0];
    const float* ef   = (const float*)d_in[1];
    const float* t    = (const float*)d_in[2];
    const float* raw  = (const float*)d_in[3];
    const float* prot = (const float*)d_in[4];
    const float* pg   = (const float*)d_in[5];
    const float* pb   = (const float*)d_in[6];
    const float* tw   = (const float*)d_in[7];
    const float* tb   = (const float*)d_in[8];
    const float* ew   = (const float*)d_in[9];
    const float* eb   = (const float*)d_in[10];
    const float* qw   = (const float*)d_in[11];
    const float* qb   = (const float*)d_in[12];
    const float* cg   = (const float*)d_in[13];
    const float* cb   = (const float*)d_in[14];
    const float* gw   = (const float*)d_in[15];
    const float* gb   = (const float*)d_in[16];
    const float* temp = (const float*)d_in[17];
    float* ws  = (float*)d_ws;
    float* out = (float*)d_out;
    const int Btot = in_sizes[0];

    hipLaunchKernelGGL(k0_fold, dim3(258), dim3(128), 0, stream,
                       qw, qb, ew, eb, pg, pb, ws);
    hipLaunchKernelGGL(k1_main, dim3((Btot + 255) / 256), dim3(256), 0, stream,
                       nids, ef, t, raw, prot, pg, pb, tw, tb, cg, cb, gw, gb, temp, ws, out, Btot);
}

// Round 2
// 514.195 us; speedup vs baseline: 1.2553x; 1.2553x over previous
//
#include <hip/hip_runtime.h>

#define D 128
#define EDIM 64
#define TDIM 64
#define KTOT 256
#define CHUNK 32
#define NCH 8
#define NP 5
#define LN_EPS 1e-4f

__device__ __forceinline__ float clipf(float x, float lo, float hi) {
    return fminf(fmaxf(x, lo), hi);
}

// quad reduction: sum over the 4 lanes owning one element
__device__ __forceinline__ float qred(float v) {
    v += __shfl_xor(v, 1, 64);
    v += __shfl_xor(v, 2, 64);
    return v;
}

// ---------------- K0: fold weights into ws ----------------
// ws layout (floats): Wt[256*128] (k-major: Wt[k][d]), c0[128], cc[3]={sgg,sgb,sbb}
__global__ void k0_fold(const float* __restrict__ qw, const float* __restrict__ qb,
                        const float* __restrict__ ew, const float* __restrict__ eb,
                        const float* __restrict__ pg, const float* __restrict__ pb,
                        float* __restrict__ ws) {
    const int d = threadIdx.x;   // 0..127
    const int bk = blockIdx.x;   // 0..257
    float* Wt = ws;
    float* c0 = ws + KTOT * D;
    float* cc = c0 + D;
    if (bk < 128) {
        Wt[bk * D + d] = qw[d * 320 + bk];
    } else if (bk < 192) {
        const int e = bk - 128;
        const float4* qrow = (const float4*)(qw + d * 320 + 128);
        float s = 0.f;
        #pragma unroll
        for (int g = 0; g < 32; ++g) {
            float4 q = qrow[g];
            s = fmaf(q.x, ew[(4 * g + 0) * EDIM + e], s);
            s = fmaf(q.y, ew[(4 * g + 1) * EDIM + e], s);
            s = fmaf(q.z, ew[(4 * g + 2) * EDIM + e], s);
            s = fmaf(q.w, ew[(4 * g + 3) * EDIM + e], s);
        }
        Wt[bk * D + d] = s;
    } else if (bk < 256) {
        Wt[bk * D + d] = qw[d * 320 + 256 + (bk - 192)];
    } else if (bk == 256) {
        const float4* qrow = (const float4*)(qw + d * 320 + 128);
        const float4* eb4 = (const float4*)eb;
        float s = qb[d];
        #pragma unroll
        for (int g = 0; g < 32; ++g) {
            float4 q = qrow[g], e4 = eb4[g];
            s = fmaf(q.x, e4.x, s); s = fmaf(q.y, e4.y, s);
            s = fmaf(q.z, e4.z, s); s = fmaf(q.w, e4.w, s);
        }
        c0[d] = s;
    } else {
        if (d == 0) { float s = 0.f; for (int i = 0; i < D; ++i) s = fmaf(pg[i], pg[i], s); cc[0] = s; }
        if (d == 1) { float s = 0.f; for (int i = 0; i < D; ++i) s = fmaf(pg[i], pb[i], s); cc[1] = s; }
        if (d == 2) { float s = 0.f; for (int i = 0; i < D; ++i) s = fmaf(pb[i], pb[i], s); cc[2] = s; }
    }
}

// GEMM micro-step: one k, 8 owned float4 output dims
__device__ __forceinline__ void kstep(const float4* __restrict__ Wb, int kbase,
                                      float vk, float4 acc[8]) {
    #pragma unroll
    for (int i = 0; i < 8; ++i) {
        float4 w = Wb[kbase + 4 * i];
        acc[i].x = fmaf(vk, w.x, acc[i].x);
        acc[i].y = fmaf(vk, w.y, acc[i].y);
        acc[i].z = fmaf(vk, w.z, acc[i].z);
        acc[i].w = fmaf(vk, w.w, acc[i].w);
    }
}

// ---------------- K1: fused main kernel, 4 lanes per batch element ----------------
// quad q = tid&3 owns float4 indices f = 4*i+q (i in [0,8)) of every 128-dim row.
__global__ __launch_bounds__(256, 4)
void k1_main(const int* __restrict__ nids, const float* __restrict__ ef,
             const float* __restrict__ tarr, const float* __restrict__ raw_mem,
             const float* __restrict__ protos,
             const float* __restrict__ pg, const float* __restrict__ pb,
             const float* __restrict__ tw, const float* __restrict__ tb,
             const float* __restrict__ cg, const float* __restrict__ cb,
             const float* __restrict__ gw, const float* __restrict__ gb,
             const float* __restrict__ temp, const float* __restrict__ ws,
             float* __restrict__ out, int Btot) {
    __shared__ float4 Wbuf[CHUNK * 32];     // 16KB, [k][32 float4]
    __shared__ float2 pgb2[D];              // {g, b} proto LN
    __shared__ float2 u12[D];               // {g*g, g*b}
    __shared__ float2 cgb2[D];              // {g, b} cell LN
    __shared__ float2 ttb[TDIM];            // {tw, tb}
    __shared__ float gwb[2 * D + TDIM];     // gate weights

    const int tid = threadIdx.x;
    const int q = tid & 3;
    const int e = tid >> 2;
    int b = blockIdx.x * 64 + e;
    const bool active = (b < Btot);
    if (!active) b = Btot - 1;

    if (tid < D) {
        float g = pg[tid], bb = pb[tid];
        pgb2[tid] = make_float2(g, bb);
        u12[tid] = make_float2(g * g, g * bb);
        cgb2[tid] = make_float2(cg[tid], cb[tid]);
    }
    if (tid < TDIM) ttb[tid] = make_float2(tw[tid], tb[tid]);
    gwb[tid] = gw[tid];
    if (tid < 2 * D + TDIM - 256) gwb[tid + 256] = gw[tid + 256];

    const int nid = nids[b];
    const float tval = tarr[b];
    const float* c0 = ws + KTOT * D;
    const float* cc = c0 + D;
    const float tempc = fminf(fmaxf(temp[0], 0.05f), 2.0f) + 1e-4f;
    const float its = 1.0f / tempc;
    const float gateb = gb[0];

    const float* rawrow = raw_mem + (size_t)nid * D;
    const float* efrow = ef + (size_t)b * EDIM;

    // acc: 8 owned float4s, init with folded bias c0
    float4 acc[8];
    {
        const float4* c04 = (const float4*)c0;
        #pragma unroll
        for (int i = 0; i < 8; ++i) acc[i] = c04[4 * i + q];
    }

    float graw = 0.f, gte = 0.f;   // full-dim gate partials (redundant across quad)

    // ---- GEMM phase: q_pre = W' @ [raw, ef, te] + c0 ----
    #pragma unroll 1
    for (int c = 0; c < NCH; ++c) {
        __syncthreads();
        {   // stage W chunk (coalesced, 4 float4 per thread)
            const float4* wsrc = (const float4*)(ws + c * CHUNK * D);
            #pragma unroll
            for (int r = 0; r < 4; ++r) Wbuf[r * 256 + tid] = wsrc[r * 256 + tid];
        }
        float4 v[8];   // this element's 32 v-values (all quad lanes load same addrs)
        if (c < 4) {
            const float4* src = (const float4*)(rawrow + c * CHUNK);
            #pragma unroll
            for (int g = 0; g < 8; ++g) v[g] = src[g];
            #pragma unroll
            for (int g = 0; g < 8; ++g) {
                const int k0 = c * CHUNK + 4 * g;
                graw = fmaf(gwb[k0 + 0], v[g].x, graw);
                graw = fmaf(gwb[k0 + 1], v[g].y, graw);
                graw = fmaf(gwb[k0 + 2], v[g].z, graw);
                graw = fmaf(gwb[k0 + 3], v[g].w, graw);
            }
        } else if (c < 6) {
            const float4* src = (const float4*)(efrow + (c - 4) * CHUNK);
            #pragma unroll
            for (int g = 0; g < 8; ++g) v[g] = src[g];
        } else {
            #pragma unroll
            for (int g = 0; g < 8; ++g) {
                const int u0 = (c - 6) * CHUNK + 4 * g;
                float2 w0 = ttb[u0], w1 = ttb[u0 + 1], w2 = ttb[u0 + 2], w3 = ttb[u0 + 3];
                float4 tv;
                tv.x = __cosf(fmaf(tval, w0.x, w0.y));
                tv.y = __cosf(fmaf(tval, w1.x, w1.y));
                tv.z = __cosf(fmaf(tval, w2.x, w2.y));
                tv.w = __cosf(fmaf(tval, w3.x, w3.y));
                gte = fmaf(gwb[2 * D + u0 + 0], tv.x, gte);
                gte = fmaf(gwb[2 * D + u0 + 1], tv.y, gte);
                gte = fmaf(gwb[2 * D + u0 + 2], tv.z, gte);
                gte = fmaf(gwb[2 * D + u0 + 3], tv.w, gte);
                v[g] = tv;
            }
        }
        __syncthreads();
        #pragma unroll
        for (int g = 0; g < 8; ++g) {
            kstep(Wbuf, (4 * g + 0) * 32 + q, v[g].x, acc);
            kstep(Wbuf, (4 * g + 1) * 32 + q, v[g].y, acc);
            kstep(Wbuf, (4 * g + 2) * 32 + q, v[g].z, acc);
            kstep(Wbuf, (4 * g + 3) * 32 + q, v[g].w, acc);
        }
    }

    // ---- query = tanh(LN(q_pre)); then acc <- qn*g ----
    float sx = 0.f;
    #pragma unroll
    for (int i = 0; i < 8; ++i) sx += (acc[i].x + acc[i].y) + (acc[i].z + acc[i].w);
    sx = qred(sx);
    const float mu = sx * (1.f / D);
    float sv = 0.f;
    #pragma unroll
    for (int i = 0; i < 8; ++i) {
        float a = acc[i].x - mu, b2 = acc[i].y - mu, c2 = acc[i].z - mu, e2 = acc[i].w - mu;
        sv = fmaf(a, a, sv); sv = fmaf(b2, b2, sv); sv = fmaf(c2, c2, sv); sv = fmaf(e2, e2, sv);
    }
    sv = qred(sv);
    const float var = sv * (1.f / D);
    const float rsq = __builtin_amdgcn_rsqf(var + LN_EPS);

    float ssq = 0.f;
    #pragma unroll
    for (int i = 0; i < 8; ++i) {
        const int d0 = (4 * i + q) * 4;
        float* a = (float*)&acc[i];
        #pragma unroll
        for (int j = 0; j < 4; ++j) {
            float2 gbv = cgb2[d0 + j];
            float x = fmaf((a[j] - mu) * rsq, gbv.x, gbv.y);
            float e2x = __expf(2.f * x);
            float th = 1.f - 2.f * __builtin_amdgcn_rcpf(e2x + 1.f);
            a[j] = th;
            ssq = fmaf(th, th, ssq);
        }
    }
    ssq = qred(ssq);
    const float invq = __builtin_amdgcn_rcpf(fmaxf(sqrtf(ssq), 1e-6f));

    float aqg = 0.f, aqb = 0.f;
    #pragma unroll
    for (int i = 0; i < 8; ++i) {
        const int d0 = (4 * i + q) * 4;
        float* a = (float*)&acc[i];
        #pragma unroll
        for (int j = 0; j < 4; ++j) {
            float2 gbv = pgb2[d0 + j];
            float qn = a[j] * invq;
            float qg = qn * gbv.x;
            aqg += qg;
            aqb = fmaf(qn, gbv.y, aqb);
            a[j] = qg;   // acc now holds qn*g at owned dims
        }
    }
    aqg = qred(aqg);
    aqb = qred(aqb);

    // ---- pass 1 over prototypes: LN stats + cosine sim (streaming) ----
    const float sgg = cc[0], sgb = cc[1], sbb = cc[2];
    const float4* pr4 = (const float4*)(protos + (size_t)nid * (NP * D));
    float mups[NP], rsps[NP], simv[NP];
    #pragma unroll
    for (int p = 0; p < NP; ++p) {
        float s_x = 0.f, sxx = 0.f, sgx2 = 0.f, sgx = 0.f, sgbx = 0.f, sqgx = 0.f;
        #pragma unroll
        for (int i = 0; i < 8; ++i) {
            float4 x4 = pr4[p * 32 + 4 * i + q];
            const int d0 = (4 * i + q) * 4;
            const float* a = (const float*)&acc[i];
            const float* xc = (const float*)&x4;
            #pragma unroll
            for (int j = 0; j < 4; ++j) {
                float x = xc[j];
                float2 u = u12[d0 + j];
                s_x += x;
                sxx = fmaf(x, x, sxx);
                sgx2 = fmaf(u.x, x * x, sgx2);
                sgx = fmaf(u.x, x, sgx);
                sgbx = fmaf(u.y, x, sgbx);
                sqgx = fmaf(a[j], x, sqgx);
            }
        }
        s_x = qred(s_x); sxx = qred(sxx); sgx2 = qred(sgx2);
        sgx = qred(sgx); sgbx = qred(sgbx); sqgx = qred(sqgx);
        const float mup = s_x * (1.f / D);
        const float varp = sxx * (1.f / D) - mup * mup;
        const float rsp = __builtin_amdgcn_rsqf(varp + LN_EPS);
        const float dot = fmaf(rsp, sqgx - mup * aqg, aqb);
        float nrm2 = rsp * rsp * (sgx2 - 2.f * mup * sgx + mup * mup * sgg)
                   + 2.f * rsp * (sgbx - mup * sgb) + sbb;
        nrm2 = fmaxf(nrm2, 0.f);
        const float inv = __builtin_amdgcn_rcpf(fmaxf(sqrtf(nrm2), 1e-6f));
        mups[p] = mup;
        rsps[p] = rsp;
        simv[p] = clipf(dot * inv, -30.f, 30.f) * its;
    }

    // ---- softmax over 5 prototypes (redundant per lane, all in regs) ----
    float mx = fmaxf(fmaxf(fmaxf(simv[0], simv[1]), fmaxf(simv[2], simv[3])), simv[4]);
    float wp[NP];
    float Z = 0.f;
    #pragma unroll
    for (int p = 0; p < NP; ++p) { float ev = __expf(simv[p] - mx); wp[p] = ev; Z += ev; }
    const float iZ = 1.f / Z;
    float a0 = 0.f, a1 = 0.f;
    #pragma unroll
    for (int p = 0; p < NP; ++p) {
        float at = wp[p] * iZ;
        a0 += at;
        float w = at * rsps[p];
        a1 = fmaf(w, mups[p], a1);
        wp[p] = w;
    }

    // ---- pass 2: S = sum_p wp * x (L2-warm reload) ----
    #pragma unroll
    for (int i = 0; i < 8; ++i) acc[i] = make_float4(0.f, 0.f, 0.f, 0.f);
    #pragma unroll
    for (int p = 0; p < NP; ++p) {
        #pragma unroll
        for (int i = 0; i < 8; ++i) {
            float4 x4 = pr4[p * 32 + 4 * i + q];
            acc[i].x = fmaf(wp[p], x4.x, acc[i].x);
            acc[i].y = fmaf(wp[p], x4.y, acc[i].y);
            acc[i].z = fmaf(wp[p], x4.z, acc[i].z);
            acc[i].w = fmaf(wp[p], x4.w, acc[i].w);
        }
    }

    // ---- cand + gate ----
    float gcand = 0.f;
    #pragma unroll
    for (int i = 0; i < 8; ++i) {
        const int d0 = (4 * i + q) * 4;
        float* a = (float*)&acc[i];
        #pragma unroll
        for (int j = 0; j < 4; ++j) {
            float2 gbv = pgb2[d0 + j];
            float cnd = clipf(fmaf(gbv.x, a[j] - a1, gbv.y * a0), -5.f, 5.f);
            gcand = fmaf(gwb[D + d0 + j], cnd, gcand);
            a[j] = cnd;
        }
    }
    gcand = qred(gcand);
    const float gpre = graw + gcand + gte + gateb;
    const float gate = __builtin_amdgcn_rcpf(1.f + __expf(-gpre));

    // ---- upd = raw + gate*(cand-raw); LN; clip; store ----
    float su = 0.f, ssu = 0.f;
    {
        const float4* rr4 = (const float4*)rawrow;
        #pragma unroll
        for (int i = 0; i < 8; ++i) {
            float4 r4 = rr4[4 * i + q];
            float* a = (float*)&acc[i];
            const float* rc = (const float*)&r4;
            #pragma unroll
            for (int j = 0; j < 4; ++j) {
                float u = fmaf(gate, a[j] - rc[j], rc[j]);
                a[j] = u;
                su += u;
                ssu = fmaf(u, u, ssu);
            }
        }
    }
    su = qred(su);
    ssu = qred(ssu);
    const float muu = su * (1.f / D);
    const float varu = ssu * (1.f / D) - muu * muu;
    const float rsu = __builtin_amdgcn_rsqf(varu + LN_EPS);

    if (active) {
        float4* orow = (float4*)(out + (size_t)b * D);
        #pragma unroll
        for (int i = 0; i < 8; ++i) {
            const int d0 = (4 * i + q) * 4;
            const float* a = (const float*)&acc[i];
            float4 o;
            float* oc = (float*)&o;
            #pragma unroll
            for (int j = 0; j < 4; ++j) {
                float2 gbv = cgb2[d0 + j];
                oc[j] = clipf(fmaf((a[j] - muu) * rsu, gbv.x, gbv.y), -10.f, 10.f);
            }
            orow[4 * i + q] = o;
        }
    }
}

extern "C" void kernel_launch(void* const* d_in, const int* in_sizes, int n_in,
                              void* d_out, int out_size, void* d_ws, size_t ws_size,
                              hipStream_t stream) {
    const int*   nids = (const int*)d_in[0];
    const float* ef   = (const float*)d_in[1];
    const float* t    = (const float*)d_in[2];
    const float* raw  = (const float*)d_in[3];
    const float* prot = (const float*)d_in[4];
    const float* pg   = (const float*)d_in[5];
    const float* pb   = (const float*)d_in[6];
    const float* tw   = (const float*)d_in[7];
    const float* tb   = (const float*)d_in[8];
    const float* ew   = (const float*)d_in[9];
    const float* eb   = (const float*)d_in[10];
    const float* qw   = (const float*)d_in[11];
    const float* qb   = (const float*)d_in[12];
    const float* cg   = (const float*)d_in[13];
    const float* cb   = (const float*)d_in[14];
    const float* gw   = (const float*)d_in[15];
    const float* gb   = (const float*)d_in[16];
    const float* temp = (const float*)d_in[17];
    float* ws  = (float*)d_ws;
    float* out = (float*)d_out;
    const int Btot = in_sizes[0];

    hipLaunchKernelGGL(k0_fold, dim3(258), dim3(128), 0, stream,
                       qw, qb, ew, eb, pg, pb, ws);
    hipLaunchKernelGGL(k1_main, dim3((Btot + 63) / 64), dim3(256), 0, stream,
                       nids, ef, t, raw, prot, pg, pb, tw, tb, cg, cb, gw, gb, temp, ws, out, Btot);
}

// Round 3
// 302.975 us; speedup vs baseline: 2.1304x; 1.6971x over previous
//
#include <hip/hip_runtime.h>

#define D 128
#define EDIM 64
#define TDIM 64
#define KTOT 256
#define CHUNK 32
#define NCH 8
#define NP 5
#define EPB 16
#define LN_EPS 1e-4f

__device__ __forceinline__ float clipf(float x, float lo, float hi) {
    return fminf(fmaxf(x, lo), hi);
}

// reduction across the 16 lanes owning one element
__device__ __forceinline__ float qred16(float v) {
    v += __shfl_xor(v, 1, 64);
    v += __shfl_xor(v, 2, 64);
    v += __shfl_xor(v, 4, 64);
    v += __shfl_xor(v, 8, 64);
    return v;
}

#define AXPY4(ACC, S, V) \
    ACC.x = fmaf(S, V.x, ACC.x); ACC.y = fmaf(S, V.y, ACC.y); \
    ACC.z = fmaf(S, V.z, ACC.z); ACC.w = fmaf(S, V.w, ACC.w);

#define DOT4(ACC, X, Y) \
    ACC = fmaf(X.x, Y.x, ACC); ACC = fmaf(X.y, Y.y, ACC); \
    ACC = fmaf(X.z, Y.z, ACC); ACC = fmaf(X.w, Y.w, ACC);

#define SQ4(ACC, X) \
    ACC = fmaf(X.x, X.x, ACC); ACC = fmaf(X.y, X.y, ACC); \
    ACC = fmaf(X.z, X.z, ACC); ACC = fmaf(X.w, X.w, ACC);

// ---------------- K0: fold weights into ws ----------------
// ws layout (floats): Wt[256*128] (k-major: Wt[k][d]), c0[128], cc[3]={sgg,sgb,sbb}
__global__ void k0_fold(const float* __restrict__ qw, const float* __restrict__ qb,
                        const float* __restrict__ ew, const float* __restrict__ eb,
                        const float* __restrict__ pg, const float* __restrict__ pb,
                        float* __restrict__ ws) {
    const int d = threadIdx.x;   // 0..127
    const int bk = blockIdx.x;   // 0..257
    float* Wt = ws;
    float* c0 = ws + KTOT * D;
    float* cc = c0 + D;
    if (bk < 128) {
        Wt[bk * D + d] = qw[d * 320 + bk];
    } else if (bk < 192) {
        const int e = bk - 128;
        const float4* qrow = (const float4*)(qw + d * 320 + 128);
        float s = 0.f;
        #pragma unroll
        for (int g = 0; g < 32; ++g) {
            float4 q = qrow[g];
            s = fmaf(q.x, ew[(4 * g + 0) * EDIM + e], s);
            s = fmaf(q.y, ew[(4 * g + 1) * EDIM + e], s);
            s = fmaf(q.z, ew[(4 * g + 2) * EDIM + e], s);
            s = fmaf(q.w, ew[(4 * g + 3) * EDIM + e], s);
        }
        Wt[bk * D + d] = s;
    } else if (bk < 256) {
        Wt[bk * D + d] = qw[d * 320 + 256 + (bk - 192)];
    } else if (bk == 256) {
        const float4* qrow = (const float4*)(qw + d * 320 + 128);
        const float4* eb4 = (const float4*)eb;
        float s = qb[d];
        #pragma unroll
        for (int g = 0; g < 32; ++g) {
            float4 q = qrow[g], e4 = eb4[g];
            s = fmaf(q.x, e4.x, s); s = fmaf(q.y, e4.y, s);
            s = fmaf(q.z, e4.z, s); s = fmaf(q.w, e4.w, s);
        }
        c0[d] = s;
    } else {
        if (d == 0) { float s = 0.f; for (int i = 0; i < D; ++i) s = fmaf(pg[i], pg[i], s); cc[0] = s; }
        if (d == 1) { float s = 0.f; for (int i = 0; i < D; ++i) s = fmaf(pg[i], pb[i], s); cc[1] = s; }
        if (d == 2) { float s = 0.f; for (int i = 0; i < D; ++i) s = fmaf(pb[i], pb[i], s); cc[2] = s; }
    }
}

// ---------------- K1: fused main kernel, 16 lanes per batch element ----------------
// lane q = tid&15 owns float4 indices {q, q+16} of each 32-float4 row,
// i.e. dims [4q..4q+3] and [64+4q..64+4q+3].
__global__ __launch_bounds__(256, 4)
void k1_main(const int* __restrict__ nids, const float* __restrict__ ef,
             const float* __restrict__ tarr, const float* __restrict__ raw_mem,
             const float* __restrict__ protos,
             const float* __restrict__ pg, const float* __restrict__ pb,
             const float* __restrict__ tw, const float* __restrict__ tb,
             const float* __restrict__ cg, const float* __restrict__ cb,
             const float* __restrict__ gw, const float* __restrict__ gb,
             const float* __restrict__ temp, const float* __restrict__ ws,
             float* __restrict__ out, int Btot) {
    __shared__ float4 Wbuf[CHUNK * 32];        // 16 KB: [k][32 float4]
    __shared__ float  vbuf[EPB][33];           // raw/ef values, padded
    __shared__ float  tebuf[EPB][TDIM + 1];    // time encoding per elem

    const int tid = threadIdx.x;
    const int q = tid & 15;
    const int e = tid >> 4;
    const int b0 = blockIdx.x * EPB;
    const int b = b0 + e;
    const bool active = (b < Btot);
    const int bb = active ? b : (Btot - 1);

    // ---- time encoding -> tebuf (this lane writes tebuf[e][4q..4q+3]) ----
    const float tval = tarr[bb];
    float4 te4;
    {
        const float4 tw4 = *(const float4*)(tw + 4 * q);
        const float4 tb4 = *(const float4*)(tb + 4 * q);
        te4.x = __cosf(fmaf(tval, tw4.x, tb4.x));
        te4.y = __cosf(fmaf(tval, tw4.y, tb4.y));
        te4.z = __cosf(fmaf(tval, tw4.z, tb4.z));
        te4.w = __cosf(fmaf(tval, tw4.w, tb4.w));
        tebuf[e][4 * q + 0] = te4.x;
        tebuf[e][4 * q + 1] = te4.y;
        tebuf[e][4 * q + 2] = te4.z;
        tebuf[e][4 * q + 3] = te4.w;
    }

    const int nid = nids[bb];
    const float* rawrow = raw_mem + (size_t)nid * D;
    const float* prow = protos + (size_t)nid * (NP * D);

    // prefetch own raw dims + all 5 prototypes' own dims into registers
    const float4 rw0 = *(const float4*)(rawrow + 4 * q);
    const float4 rw1 = *(const float4*)(rawrow + 64 + 4 * q);
    float4 px[NP][2];
    #pragma unroll
    for (int p = 0; p < NP; ++p) {
        px[p][0] = *(const float4*)(prow + p * D + 4 * q);
        px[p][1] = *(const float4*)(prow + p * D + 64 + 4 * q);
    }

    // acc init with folded bias c0
    const float* c0 = ws + KTOT * D;
    float4 acc0 = *(const float4*)(c0 + 4 * q);
    float4 acc1 = *(const float4*)(c0 + 64 + 4 * q);

    // ---- GEMM: q_pre = W' @ [raw, ef, te] + c0 ----
    #pragma unroll 1
    for (int c = 0; c < NCH; ++c) {
        __syncthreads();
        {   // stage W chunk (coalesced, 4 float4/thread)
            const float4* wsrc = (const float4*)(ws + (size_t)c * CHUNK * D);
            Wbuf[tid]       = wsrc[tid];
            Wbuf[tid + 256] = wsrc[tid + 256];
            Wbuf[tid + 512] = wsrc[tid + 512];
            Wbuf[tid + 768] = wsrc[tid + 768];
        }
        if (c < 4) {
            if (tid < 128) {
                const int se = tid >> 3, si = tid & 7;
                const int sb = b0 + se < Btot ? b0 + se : Btot - 1;
                const int snid = nids[sb];
                const float4 x = *(const float4*)(raw_mem + (size_t)snid * D + c * CHUNK + 4 * si);
                float* vd = &vbuf[se][4 * si];
                vd[0] = x.x; vd[1] = x.y; vd[2] = x.z; vd[3] = x.w;
            }
        } else if (c < 6) {
            if (tid < 128) {
                const int se = tid >> 3, si = tid & 7;
                const size_t sb = (size_t)(b0 + se < Btot ? b0 + se : Btot - 1);
                const float4 x = *(const float4*)(ef + sb * EDIM + (c - 4) * CHUNK + 4 * si);
                float* vd = &vbuf[se][4 * si];
                vd[0] = x.x; vd[1] = x.y; vd[2] = x.z; vd[3] = x.w;
            }
        }
        __syncthreads();
        const float* vsrc = (c < 6) ? &vbuf[e][0] : &tebuf[e][(c & 1) * CHUNK];
        #pragma unroll
        for (int k = 0; k < CHUNK; ++k) {
            const float vk = vsrc[k];
            const float4 w0 = Wbuf[k * 32 + q];
            const float4 w1 = Wbuf[k * 32 + 16 + q];
            AXPY4(acc0, vk, w0);
            AXPY4(acc1, vk, w1);
        }
    }

    // ---- gate partials: raw and te shares (this lane's indices) ----
    float gsum = 0.f;   // accumulates graw + gte + gcand, reduced once at the end
    {
        const float4 g0 = *(const float4*)(gw + 4 * q);
        const float4 g1 = *(const float4*)(gw + 64 + 4 * q);
        gsum = fmaf(g0.x, clipf(rw0.x, -100.f, 100.f), gsum);
        gsum = fmaf(g0.y, clipf(rw0.y, -100.f, 100.f), gsum);
        gsum = fmaf(g0.z, clipf(rw0.z, -100.f, 100.f), gsum);
        gsum = fmaf(g0.w, clipf(rw0.w, -100.f, 100.f), gsum);
        gsum = fmaf(g1.x, clipf(rw1.x, -100.f, 100.f), gsum);
        gsum = fmaf(g1.y, clipf(rw1.y, -100.f, 100.f), gsum);
        gsum = fmaf(g1.z, clipf(rw1.z, -100.f, 100.f), gsum);
        gsum = fmaf(g1.w, clipf(rw1.w, -100.f, 100.f), gsum);
        const float4 gt = *(const float4*)(gw + 2 * D + 4 * q);
        DOT4(gsum, gt, te4);
    }

    // ---- query = tanh(LN(q_pre)) ----
    float sx = (acc0.x + acc0.y) + (acc0.z + acc0.w) + (acc1.x + acc1.y) + (acc1.z + acc1.w);
    sx = qred16(sx);
    const float mu = sx * (1.f / D);
    float sv = 0.f;
    {
        float a;
        a = acc0.x - mu; sv = fmaf(a, a, sv);
        a = acc0.y - mu; sv = fmaf(a, a, sv);
        a = acc0.z - mu; sv = fmaf(a, a, sv);
        a = acc0.w - mu; sv = fmaf(a, a, sv);
        a = acc1.x - mu; sv = fmaf(a, a, sv);
        a = acc1.y - mu; sv = fmaf(a, a, sv);
        a = acc1.z - mu; sv = fmaf(a, a, sv);
        a = acc1.w - mu; sv = fmaf(a, a, sv);
    }
    sv = qred16(sv);
    const float rsq = __builtin_amdgcn_rsqf(sv * (1.f / D) + LN_EPS);

    const float4 cgA = *(const float4*)(cg + 4 * q);
    const float4 cgB = *(const float4*)(cg + 64 + 4 * q);
    const float4 cbA = *(const float4*)(cb + 4 * q);
    const float4 cbB = *(const float4*)(cb + 64 + 4 * q);

    float ssq = 0.f;
#define TANH_STEP(AM, GM, BM) { \
        float x_ = fmaf((AM - mu) * rsq, GM, BM); \
        float e_ = __expf(2.f * x_); \
        AM = 1.f - 2.f * __builtin_amdgcn_rcpf(e_ + 1.f); \
        ssq = fmaf(AM, AM, ssq); }
    TANH_STEP(acc0.x, cgA.x, cbA.x) TANH_STEP(acc0.y, cgA.y, cbA.y)
    TANH_STEP(acc0.z, cgA.z, cbA.z) TANH_STEP(acc0.w, cgA.w, cbA.w)
    TANH_STEP(acc1.x, cgB.x, cbB.x) TANH_STEP(acc1.y, cgB.y, cbB.y)
    TANH_STEP(acc1.z, cgB.z, cbB.z) TANH_STEP(acc1.w, cgB.w, cbB.w)
    ssq = qred16(ssq);
    const float invq = __builtin_amdgcn_rcpf(fmaxf(sqrtf(ssq), 1e-6f));

    // proto-LN gamma/beta for owned dims
    const float4 pgA = *(const float4*)(pg + 4 * q);
    const float4 pgB = *(const float4*)(pg + 64 + 4 * q);
    const float4 pbA = *(const float4*)(pb + 4 * q);
    const float4 pbB = *(const float4*)(pb + 64 + 4 * q);

    // acc <- qn*g ; aqg = sum(qn*g), aqb = sum(qn*b)
    float aqg = 0.f, aqb = 0.f;
#define QG_STEP(AM, GM, BM) { \
        float qn_ = AM * invq; \
        AM = qn_ * GM; \
        aqg += AM; \
        aqb = fmaf(qn_, BM, aqb); }
    QG_STEP(acc0.x, pgA.x, pbA.x) QG_STEP(acc0.y, pgA.y, pbA.y)
    QG_STEP(acc0.z, pgA.z, pbA.z) QG_STEP(acc0.w, pgA.w, pbA.w)
    QG_STEP(acc1.x, pgB.x, pbB.x) QG_STEP(acc1.y, pgB.y, pbB.y)
    QG_STEP(acc1.z, pgB.z, pbB.z) QG_STEP(acc1.w, pgB.w, pbB.w)
    aqg = qred16(aqg);
    aqb = qred16(aqb);

    // ---- per-proto LN stats + cosine sim, all from register-resident px ----
    const float sbb = (ws + KTOT * D + D)[2];
    const float tempc = fminf(fmaxf(temp[0], 0.05f), 2.0f) + 1e-4f;
    const float its = 1.0f / tempc;
    float mups[NP], rsps[NP], simv[NP];
    #pragma unroll
    for (int p = 0; p < NP; ++p) {
        float s_x = (px[p][0].x + px[p][0].y) + (px[p][0].z + px[p][0].w)
                  + (px[p][1].x + px[p][1].y) + (px[p][1].z + px[p][1].w);
        float sxx = 0.f, sqgx = 0.f;
        SQ4(sxx, px[p][0]) SQ4(sxx, px[p][1])
        DOT4(sqgx, acc0, px[p][0]) DOT4(sqgx, acc1, px[p][1])
        s_x = qred16(s_x); sxx = qred16(sxx); sqgx = qred16(sqgx);
        const float mup = s_x * (1.f / D);
        const float varp = sxx * (1.f / D) - mup * mup;
        const float rsp = __builtin_amdgcn_rsqf(varp + LN_EPS);
        float sz2 = 0.f, szb = 0.f;
#define ZSTEP(XM, GM, BM) { \
        float z_ = (XM - mup) * GM; \
        sz2 = fmaf(z_, z_, sz2); \
        szb = fmaf(z_, BM, szb); }
        ZSTEP(px[p][0].x, pgA.x, pbA.x) ZSTEP(px[p][0].y, pgA.y, pbA.y)
        ZSTEP(px[p][0].z, pgA.z, pbA.z) ZSTEP(px[p][0].w, pgA.w, pbA.w)
        ZSTEP(px[p][1].x, pgB.x, pbB.x) ZSTEP(px[p][1].y, pgB.y, pbB.y)
        ZSTEP(px[p][1].z, pgB.z, pbB.z) ZSTEP(px[p][1].w, pgB.w, pbB.w)
        sz2 = qred16(sz2); szb = qred16(szb);
        const float dot = fmaf(rsp, sqgx - mup * aqg, aqb);
        float nrm2 = fmaf(rsp * rsp, sz2, fmaf(2.f * rsp, szb, sbb));
        nrm2 = fmaxf(nrm2, 0.f);
        const float inv = __builtin_amdgcn_rcpf(fmaxf(sqrtf(nrm2), 1e-6f));
        mups[p] = mup;
        rsps[p] = rsp;
        simv[p] = clipf(dot * inv, -30.f, 30.f) * its;
    }

    // ---- softmax over 5 (redundant per lane) ----
    float mx = fmaxf(fmaxf(fmaxf(simv[0], simv[1]), fmaxf(simv[2], simv[3])), simv[4]);
    float wp[NP];
    float Z = 0.f;
    #pragma unroll
    for (int p = 0; p < NP; ++p) { float ev = __expf(simv[p] - mx); wp[p] = ev; Z += ev; }
    const float iZ = 1.f / Z;
    float a0 = 0.f, a1 = 0.f;
    #pragma unroll
    for (int p = 0; p < NP; ++p) {
        float at = wp[p] * iZ;
        a0 += at;
        float w = at * rsps[p];
        a1 = fmaf(w, mups[p], a1);
        wp[p] = w;
    }

    // ---- weighted proto sum from registers ----
    float4 S0 = make_float4(0.f, 0.f, 0.f, 0.f);
    float4 S1 = make_float4(0.f, 0.f, 0.f, 0.f);
    #pragma unroll
    for (int p = 0; p < NP; ++p) {
        AXPY4(S0, wp[p], px[p][0]);
        AXPY4(S1, wp[p], px[p][1]);
    }

    // ---- cand + gate contribution ----
    const float4 gc0 = *(const float4*)(gw + D + 4 * q);
    const float4 gc1 = *(const float4*)(gw + D + 64 + 4 * q);
#define CAND_STEP(SM, GM, BM, GWm) { \
        SM = clipf(fmaf(GM, SM - a1, BM * a0), -5.f, 5.f); \
        gsum = fmaf(GWm, SM, gsum); }
    CAND_STEP(S0.x, pgA.x, pbA.x, gc0.x) CAND_STEP(S0.y, pgA.y, pbA.y, gc0.y)
    CAND_STEP(S0.z, pgA.z, pbA.z, gc0.z) CAND_STEP(S0.w, pgA.w, pbA.w, gc0.w)
    CAND_STEP(S1.x, pgB.x, pbB.x, gc1.x) CAND_STEP(S1.y, pgB.y, pbB.y, gc1.y)
    CAND_STEP(S1.z, pgB.z, pbB.z, gc1.z) CAND_STEP(S1.w, pgB.w, pbB.w, gc1.w)
    gsum = qred16(gsum);
    const float gpre = gsum + gb[0];
    const float gate = __builtin_amdgcn_rcpf(1.f + __expf(-gpre));

    // ---- upd = raw + gate*(cand - raw); LN; clip; store ----
    float su = 0.f, ssu = 0.f;
#define BLEND_STEP(SM, RM) { \
        SM = fmaf(gate, SM - RM, RM); \
        su += SM; \
        ssu = fmaf(SM, SM, ssu); }
    BLEND_STEP(S0.x, rw0.x) BLEND_STEP(S0.y, rw0.y)
    BLEND_STEP(S0.z, rw0.z) BLEND_STEP(S0.w, rw0.w)
    BLEND_STEP(S1.x, rw1.x) BLEND_STEP(S1.y, rw1.y)
    BLEND_STEP(S1.z, rw1.z) BLEND_STEP(S1.w, rw1.w)
    su = qred16(su);
    ssu = qred16(ssu);
    const float muu = su * (1.f / D);
    const float varu = ssu * (1.f / D) - muu * muu;
    const float rsu = __builtin_amdgcn_rsqf(varu + LN_EPS);

    if (active) {
#define OUT_STEP(SM, GM, BM) clipf(fmaf((SM - muu) * rsu, GM, BM), -10.f, 10.f)
        float4 o0, o1;
        o0.x = OUT_STEP(S0.x, cgA.x, cbA.x); o0.y = OUT_STEP(S0.y, cgA.y, cbA.y);
        o0.z = OUT_STEP(S0.z, cgA.z, cbA.z); o0.w = OUT_STEP(S0.w, cgA.w, cbA.w);
        o1.x = OUT_STEP(S1.x, cgB.x, cbB.x); o1.y = OUT_STEP(S1.y, cgB.y, cbB.y);
        o1.z = OUT_STEP(S1.z, cgB.z, cbB.z); o1.w = OUT_STEP(S1.w, cgB.w, cbB.w);
        *(float4*)(out + (size_t)b * D + 4 * q) = o0;
        *(float4*)(out + (size_t)b * D + 64 + 4 * q) = o1;
    }
}

extern "C" void kernel_launch(void* const* d_in, const int* in_sizes, int n_in,
                              void* d_out, int out_size, void* d_ws, size_t ws_size,
                              hipStream_t stream) {
    const int*   nids = (const int*)d_in[0];
    const float* ef   = (const float*)d_in[1];
    const float* t    = (const float*)d_in[2];
    const float* raw  = (const float*)d_in[3];
    const float* prot = (const float*)d_in[4];
    const float* pg   = (const float*)d_in[5];
    const float* pb   = (const float*)d_in[6];
    const float* tw   = (const float*)d_in[7];
    const float* tb   = (const float*)d_in[8];
    const float* ew   = (const float*)d_in[9];
    const float* eb   = (const float*)d_in[10];
    const float* qw   = (const float*)d_in[11];
    const float* qb   = (const float*)d_in[12];
    const float* cg   = (const float*)d_in[13];
    const float* cb   = (const float*)d_in[14];
    const float* gw   = (const float*)d_in[15];
    const float* gb   = (const float*)d_in[16];
    const float* temp = (const float*)d_in[17];
    float* ws  = (float*)d_ws;
    float* out = (float*)d_out;
    const int Btot = in_sizes[0];

    hipLaunchKernelGGL(k0_fold, dim3(258), dim3(128), 0, stream,
                       qw, qb, ew, eb, pg, pb, ws);
    hipLaunchKernelGGL(k1_main, dim3((Btot + EPB - 1) / EPB), dim3(256), 0, stream,
                       nids, ef, t, raw, prot, pg, pb, tw, tb, cg, cb, gw, gb, temp, ws, out, Btot);
}

// Round 4
// 217.301 us; speedup vs baseline: 2.9704x; 1.3943x over previous
//
#include <hip/hip_runtime.h>

#define D 128
#define EDIM 64
#define TDIM 64
#define KTOT 256
#define CHUNK 32
#define NCH 8
#define NP 5
#define BM 64      // elements per block, GEMM kernel
#define EPB 16     // elements per block, epilogue kernel
#define LN_EPS 1e-4f

__device__ __forceinline__ float clipf(float x, float lo, float hi) {
    return fminf(fmaxf(x, lo), hi);
}

// reduction across the 16 lanes owning one element
__device__ __forceinline__ float qred16(float v) {
    v += __shfl_xor(v, 1, 64);
    v += __shfl_xor(v, 2, 64);
    v += __shfl_xor(v, 4, 64);
    v += __shfl_xor(v, 8, 64);
    return v;
}

#define AXPY4(ACC, S, V) \
    ACC.x = fmaf(S, V.x, ACC.x); ACC.y = fmaf(S, V.y, ACC.y); \
    ACC.z = fmaf(S, V.z, ACC.z); ACC.w = fmaf(S, V.w, ACC.w);

#define DOT4(ACC, X, Y) \
    ACC = fmaf(X.x, Y.x, ACC); ACC = fmaf(X.y, Y.y, ACC); \
    ACC = fmaf(X.z, Y.z, ACC); ACC = fmaf(X.w, Y.w, ACC);

#define SQ4(ACC, X) \
    ACC = fmaf(X.x, X.x, ACC); ACC = fmaf(X.y, X.y, ACC); \
    ACC = fmaf(X.z, X.z, ACC); ACC = fmaf(X.w, X.w, ACC);

// ---------------- K0: fold weights into ws ----------------
// ws layout (floats): Wt[256*128] (k-major: Wt[k][d]), c0[128], cc[3]={sgg,sgb,sbb}
__global__ void k0_fold(const float* __restrict__ qw, const float* __restrict__ qb,
                        const float* __restrict__ ew, const float* __restrict__ eb,
                        const float* __restrict__ pg, const float* __restrict__ pb,
                        float* __restrict__ ws) {
    const int d = threadIdx.x;   // 0..127
    const int bk = blockIdx.x;   // 0..257
    float* Wt = ws;
    float* c0 = ws + KTOT * D;
    float* cc = c0 + D;
    if (bk < 128) {
        Wt[bk * D + d] = qw[d * 320 + bk];
    } else if (bk < 192) {
        const int e = bk - 128;
        const float4* qrow = (const float4*)(qw + d * 320 + 128);
        float s = 0.f;
        #pragma unroll
        for (int g = 0; g < 32; ++g) {
            float4 q = qrow[g];
            s = fmaf(q.x, ew[(4 * g + 0) * EDIM + e], s);
            s = fmaf(q.y, ew[(4 * g + 1) * EDIM + e], s);
            s = fmaf(q.z, ew[(4 * g + 2) * EDIM + e], s);
            s = fmaf(q.w, ew[(4 * g + 3) * EDIM + e], s);
        }
        Wt[bk * D + d] = s;
    } else if (bk < 256) {
        Wt[bk * D + d] = qw[d * 320 + 256 + (bk - 192)];
    } else if (bk == 256) {
        const float4* qrow = (const float4*)(qw + d * 320 + 128);
        const float4* eb4 = (const float4*)eb;
        float s = qb[d];
        #pragma unroll
        for (int g = 0; g < 32; ++g) {
            float4 q = qrow[g], e4 = eb4[g];
            s = fmaf(q.x, e4.x, s); s = fmaf(q.y, e4.y, s);
            s = fmaf(q.z, e4.z, s); s = fmaf(q.w, e4.w, s);
        }
        c0[d] = s;
    } else {
        if (d == 0) { float s = 0.f; for (int i = 0; i < D; ++i) s = fmaf(pg[i], pg[i], s); cc[0] = s; }
        if (d == 1) { float s = 0.f; for (int i = 0; i < D; ++i) s = fmaf(pg[i], pb[i], s); cc[1] = s; }
        if (d == 2) { float s = 0.f; for (int i = 0; i < D; ++i) s = fmaf(pb[i], pb[i], s); cc[2] = s; }
    }
}

// ---------------- K_gemm: q_pre = W' @ [raw, ef, te] + c0 ----------------
// 64 elems/block; thread (dg = tid&15, eg = tid>>4) computes elems eg*4..eg*4+3
// at dims [4dg..4dg+3] and [64+4dg..64+4dg+3]. Writes q_pre into `qpre` (=d_out).
__global__ __launch_bounds__(256, 4)
void k_gemm(const int* __restrict__ nids, const float* __restrict__ ef,
            const float* __restrict__ tarr, const float* __restrict__ raw_mem,
            const float* __restrict__ tw, const float* __restrict__ tb,
            const float* __restrict__ ws, float* qpre, int Btot) {
    __shared__ float4 Wb[CHUNK * 32];      // 16 KB: [k][32 float4]
    __shared__ float  Vb[BM][CHUNK + 1];   // 8.25 KB
    __shared__ float  tvals[BM];

    const int tid = threadIdx.x;
    const int dg = tid & 15;
    const int eg = tid >> 4;
    const int b0 = blockIdx.x * BM;

    if (tid < BM) tvals[tid] = tarr[min(b0 + tid, Btot - 1)];

    const float4* c04 = (const float4*)(ws + KTOT * D);
    float4 acc[4][2];
    #pragma unroll
    for (int j = 0; j < 4; ++j) {
        acc[j][0] = c04[dg];
        acc[j][1] = c04[16 + dg];
    }

    const int m = tid >> 2;   // staged element 0..63
    const int i4 = tid & 3;   // quarter of its 32 k-values
    const int sb = min(b0 + m, Btot - 1);

    #pragma unroll 1
    for (int c = 0; c < NCH; ++c) {
        __syncthreads();
        {   // stage W chunk (coalesced, 4 float4/thread)
            const float4* wsrc = (const float4*)(ws + (size_t)c * CHUNK * D);
            Wb[tid]       = wsrc[tid];
            Wb[tid + 256] = wsrc[tid + 256];
            Wb[tid + 512] = wsrc[tid + 512];
            Wb[tid + 768] = wsrc[tid + 768];
        }
        if (c < 4) {
            const float4* src = (const float4*)(raw_mem + (size_t)nids[sb] * D + c * CHUNK);
            float4 x0 = src[i4 * 2], x1 = src[i4 * 2 + 1];
            float* vd = &Vb[m][i4 * 8];
            vd[0] = x0.x; vd[1] = x0.y; vd[2] = x0.z; vd[3] = x0.w;
            vd[4] = x1.x; vd[5] = x1.y; vd[6] = x1.z; vd[7] = x1.w;
        } else if (c < 6) {
            const float4* src = (const float4*)(ef + (size_t)sb * EDIM + (c - 4) * CHUNK);
            float4 x0 = src[i4 * 2], x1 = src[i4 * 2 + 1];
            float* vd = &Vb[m][i4 * 8];
            vd[0] = x0.x; vd[1] = x0.y; vd[2] = x0.z; vd[3] = x0.w;
            vd[4] = x1.x; vd[5] = x1.y; vd[6] = x1.z; vd[7] = x1.w;
        } else {
            const float tv = tvals[m];
            const int u0 = (c - 6) * CHUNK + i4 * 8;
            float* vd = &Vb[m][i4 * 8];
            #pragma unroll
            for (int jj = 0; jj < 8; ++jj)
                vd[jj] = __cosf(fmaf(tv, tw[u0 + jj], tb[u0 + jj]));
        }
        __syncthreads();
        #pragma unroll
        for (int k = 0; k < CHUNK; ++k) {
            const float4 w0 = Wb[k * 32 + dg];
            const float4 w1 = Wb[k * 32 + 16 + dg];
            const float v0 = Vb[eg * 4 + 0][k];
            const float v1 = Vb[eg * 4 + 1][k];
            const float v2 = Vb[eg * 4 + 2][k];
            const float v3 = Vb[eg * 4 + 3][k];
            AXPY4(acc[0][0], v0, w0); AXPY4(acc[0][1], v0, w1);
            AXPY4(acc[1][0], v1, w0); AXPY4(acc[1][1], v1, w1);
            AXPY4(acc[2][0], v2, w0); AXPY4(acc[2][1], v2, w1);
            AXPY4(acc[3][0], v3, w0); AXPY4(acc[3][1], v3, w1);
        }
    }

    #pragma unroll
    for (int j = 0; j < 4; ++j) {
        const int e = b0 + eg * 4 + j;
        if (e < Btot) {
            *(float4*)(qpre + (size_t)e * D + 4 * dg)      = acc[j][0];
            *(float4*)(qpre + (size_t)e * D + 64 + 4 * dg) = acc[j][1];
        }
    }
}

// ---------------- K_epi: everything after q_pre; 16 lanes/elem ----------------
// qpre aliases out (read early, written late, same element -> safe).
__global__ __launch_bounds__(256, 4)
void k_epi(const int* __restrict__ nids, const float* __restrict__ tarr,
           const float* __restrict__ raw_mem, const float* __restrict__ protos,
           const float* __restrict__ pg, const float* __restrict__ pb,
           const float* __restrict__ tw, const float* __restrict__ tb,
           const float* __restrict__ cg, const float* __restrict__ cb,
           const float* __restrict__ gw, const float* __restrict__ gb,
           const float* __restrict__ temp, const float* __restrict__ ws,
           float* out, int Btot) {
    const int tid = threadIdx.x;
    const int q = tid & 15;
    const int e = tid >> 4;
    const int b = blockIdx.x * EPB + e;
    const bool active = (b < Btot);
    const int bb = active ? b : (Btot - 1);

    const int nid = nids[bb];
    const float* rawrow = raw_mem + (size_t)nid * D;
    const float* prow = protos + (size_t)nid * (NP * D);

    // q_pre (from out buffer), raw, protos -> registers
    float4 acc0 = *(const float4*)(out + (size_t)bb * D + 4 * q);
    float4 acc1 = *(const float4*)(out + (size_t)bb * D + 64 + 4 * q);
    const float4 rw0 = *(const float4*)(rawrow + 4 * q);
    const float4 rw1 = *(const float4*)(rawrow + 64 + 4 * q);
    float4 px[NP][2];
    #pragma unroll
    for (int p = 0; p < NP; ++p) {
        px[p][0] = *(const float4*)(prow + p * D + 4 * q);
        px[p][1] = *(const float4*)(prow + p * D + 64 + 4 * q);
    }

    // ---- gate partials: raw and te shares ----
    float gsum = 0.f;
    {
        const float4 g0 = *(const float4*)(gw + 4 * q);
        const float4 g1 = *(const float4*)(gw + 64 + 4 * q);
        gsum = fmaf(g0.x, clipf(rw0.x, -100.f, 100.f), gsum);
        gsum = fmaf(g0.y, clipf(rw0.y, -100.f, 100.f), gsum);
        gsum = fmaf(g0.z, clipf(rw0.z, -100.f, 100.f), gsum);
        gsum = fmaf(g0.w, clipf(rw0.w, -100.f, 100.f), gsum);
        gsum = fmaf(g1.x, clipf(rw1.x, -100.f, 100.f), gsum);
        gsum = fmaf(g1.y, clipf(rw1.y, -100.f, 100.f), gsum);
        gsum = fmaf(g1.z, clipf(rw1.z, -100.f, 100.f), gsum);
        gsum = fmaf(g1.w, clipf(rw1.w, -100.f, 100.f), gsum);
        const float tval = tarr[bb];
        const float4 tw4 = *(const float4*)(tw + 4 * q);
        const float4 tb4 = *(const float4*)(tb + 4 * q);
        const float4 gt = *(const float4*)(gw + 2 * D + 4 * q);
        gsum = fmaf(gt.x, __cosf(fmaf(tval, tw4.x, tb4.x)), gsum);
        gsum = fmaf(gt.y, __cosf(fmaf(tval, tw4.y, tb4.y)), gsum);
        gsum = fmaf(gt.z, __cosf(fmaf(tval, tw4.z, tb4.z)), gsum);
        gsum = fmaf(gt.w, __cosf(fmaf(tval, tw4.w, tb4.w)), gsum);
    }

    // ---- query = tanh(LN(q_pre)) ----
    float sx = (acc0.x + acc0.y) + (acc0.z + acc0.w) + (acc1.x + acc1.y) + (acc1.z + acc1.w);
    sx = qred16(sx);
    const float mu = sx * (1.f / D);
    float sv = 0.f;
    {
        float a;
        a = acc0.x - mu; sv = fmaf(a, a, sv);
        a = acc0.y - mu; sv = fmaf(a, a, sv);
        a = acc0.z - mu; sv = fmaf(a, a, sv);
        a = acc0.w - mu; sv = fmaf(a, a, sv);
        a = acc1.x - mu; sv = fmaf(a, a, sv);
        a = acc1.y - mu; sv = fmaf(a, a, sv);
        a = acc1.z - mu; sv = fmaf(a, a, sv);
        a = acc1.w - mu; sv = fmaf(a, a, sv);
    }
    sv = qred16(sv);
    const float rsq = __builtin_amdgcn_rsqf(sv * (1.f / D) + LN_EPS);

    const float4 cgA = *(const float4*)(cg + 4 * q);
    const float4 cgB = *(const float4*)(cg + 64 + 4 * q);
    const float4 cbA = *(const float4*)(cb + 4 * q);
    const float4 cbB = *(const float4*)(cb + 64 + 4 * q);

    float ssq = 0.f;
#define TANH_STEP(AM, GM, BM_) { \
        float x_ = fmaf((AM - mu) * rsq, GM, BM_); \
        float e_ = __expf(2.f * x_); \
        AM = 1.f - 2.f * __builtin_amdgcn_rcpf(e_ + 1.f); \
        ssq = fmaf(AM, AM, ssq); }
    TANH_STEP(acc0.x, cgA.x, cbA.x) TANH_STEP(acc0.y, cgA.y, cbA.y)
    TANH_STEP(acc0.z, cgA.z, cbA.z) TANH_STEP(acc0.w, cgA.w, cbA.w)
    TANH_STEP(acc1.x, cgB.x, cbB.x) TANH_STEP(acc1.y, cgB.y, cbB.y)
    TANH_STEP(acc1.z, cgB.z, cbB.z) TANH_STEP(acc1.w, cgB.w, cbB.w)
    ssq = qred16(ssq);
    const float invq = __builtin_amdgcn_rcpf(fmaxf(sqrtf(ssq), 1e-6f));

    const float4 pgA = *(const float4*)(pg + 4 * q);
    const float4 pgB = *(const float4*)(pg + 64 + 4 * q);
    const float4 pbA = *(const float4*)(pb + 4 * q);
    const float4 pbB = *(const float4*)(pb + 64 + 4 * q);

    float aqg = 0.f, aqb = 0.f;
#define QG_STEP(AM, GM, BM_) { \
        float qn_ = AM * invq; \
        AM = qn_ * GM; \
        aqg += AM; \
        aqb = fmaf(qn_, BM_, aqb); }
    QG_STEP(acc0.x, pgA.x, pbA.x) QG_STEP(acc0.y, pgA.y, pbA.y)
    QG_STEP(acc0.z, pgA.z, pbA.z) QG_STEP(acc0.w, pgA.w, pbA.w)
    QG_STEP(acc1.x, pgB.x, pbB.x) QG_STEP(acc1.y, pgB.y, pbB.y)
    QG_STEP(acc1.z, pgB.z, pbB.z) QG_STEP(acc1.w, pgB.w, pbB.w)
    aqg = qred16(aqg);
    aqb = qred16(aqb);

    // ---- per-proto LN stats + cosine sim from register-resident px ----
    const float sbb = (ws + KTOT * D + D)[2];
    const float tempc = fminf(fmaxf(temp[0], 0.05f), 2.0f) + 1e-4f;
    const float its = 1.0f / tempc;
    float mups[NP], rsps[NP], simv[NP];
    #pragma unroll
    for (int p = 0; p < NP; ++p) {
        float s_x = (px[p][0].x + px[p][0].y) + (px[p][0].z + px[p][0].w)
                  + (px[p][1].x + px[p][1].y) + (px[p][1].z + px[p][1].w);
        float sxx = 0.f, sqgx = 0.f;
        SQ4(sxx, px[p][0]) SQ4(sxx, px[p][1])
        DOT4(sqgx, acc0, px[p][0]) DOT4(sqgx, acc1, px[p][1])
        s_x = qred16(s_x); sxx = qred16(sxx); sqgx = qred16(sqgx);
        const float mup = s_x * (1.f / D);
        const float varp = sxx * (1.f / D) - mup * mup;
        const float rsp = __builtin_amdgcn_rsqf(varp + LN_EPS);
        float sz2 = 0.f, szb = 0.f;
#define ZSTEP(XM, GM, BM_) { \
        float z_ = (XM - mup) * GM; \
        sz2 = fmaf(z_, z_, sz2); \
        szb = fmaf(z_, BM_, szb); }
        ZSTEP(px[p][0].x, pgA.x, pbA.x) ZSTEP(px[p][0].y, pgA.y, pbA.y)
        ZSTEP(px[p][0].z, pgA.z, pbA.z) ZSTEP(px[p][0].w, pgA.w, pbA.w)
        ZSTEP(px[p][1].x, pgB.x, pbB.x) ZSTEP(px[p][1].y, pgB.y, pbB.y)
        ZSTEP(px[p][1].z, pgB.z, pbB.z) ZSTEP(px[p][1].w, pgB.w, pbB.w)
        sz2 = qred16(sz2); szb = qred16(szb);
        const float dot = fmaf(rsp, sqgx - mup * aqg, aqb);
        float nrm2 = fmaf(rsp * rsp, sz2, fmaf(2.f * rsp, szb, sbb));
        nrm2 = fmaxf(nrm2, 0.f);
        const float inv = __builtin_amdgcn_rcpf(fmaxf(sqrtf(nrm2), 1e-6f));
        mups[p] = mup;
        rsps[p] = rsp;
        simv[p] = clipf(dot * inv, -30.f, 30.f) * its;
    }

    // ---- softmax over 5 (redundant per lane) ----
    float mx = fmaxf(fmaxf(fmaxf(simv[0], simv[1]), fmaxf(simv[2], simv[3])), simv[4]);
    float wp[NP];
    float Z = 0.f;
    #pragma unroll
    for (int p = 0; p < NP; ++p) { float ev = __expf(simv[p] - mx); wp[p] = ev; Z += ev; }
    const float iZ = 1.f / Z;
    float a0 = 0.f, a1 = 0.f;
    #pragma unroll
    for (int p = 0; p < NP; ++p) {
        float at = wp[p] * iZ;
        a0 += at;
        float w = at * rsps[p];
        a1 = fmaf(w, mups[p], a1);
        wp[p] = w;
    }

    // ---- weighted proto sum from registers ----
    float4 S0 = make_float4(0.f, 0.f, 0.f, 0.f);
    float4 S1 = make_float4(0.f, 0.f, 0.f, 0.f);
    #pragma unroll
    for (int p = 0; p < NP; ++p) {
        AXPY4(S0, wp[p], px[p][0]);
        AXPY4(S1, wp[p], px[p][1]);
    }

    // ---- cand + gate contribution ----
    const float4 gc0 = *(const float4*)(gw + D + 4 * q);
    const float4 gc1 = *(const float4*)(gw + D + 64 + 4 * q);
#define CAND_STEP(SM, GM, BM_, GWm) { \
        SM = clipf(fmaf(GM, SM - a1, BM_ * a0), -5.f, 5.f); \
        gsum = fmaf(GWm, SM, gsum); }
    CAND_STEP(S0.x, pgA.x, pbA.x, gc0.x) CAND_STEP(S0.y, pgA.y, pbA.y, gc0.y)
    CAND_STEP(S0.z, pgA.z, pbA.z, gc0.z) CAND_STEP(S0.w, pgA.w, pbA.w, gc0.w)
    CAND_STEP(S1.x, pgB.x, pbB.x, gc1.x) CAND_STEP(S1.y, pgB.y, pbB.y, gc1.y)
    CAND_STEP(S1.z, pgB.z, pbB.z, gc1.z) CAND_STEP(S1.w, pgB.w, pbB.w, gc1.w)
    gsum = qred16(gsum);
    const float gpre = gsum + gb[0];
    const float gate = __builtin_amdgcn_rcpf(1.f + __expf(-gpre));

    // ---- upd = raw + gate*(cand - raw); LN; clip; store ----
    float su = 0.f, ssu = 0.f;
#define BLEND_STEP(SM, RM) { \
        SM = fmaf(gate, SM - RM, RM); \
        su += SM; \
        ssu = fmaf(SM, SM, ssu); }
    BLEND_STEP(S0.x, rw0.x) BLEND_STEP(S0.y, rw0.y)
    BLEND_STEP(S0.z, rw0.z) BLEND_STEP(S0.w, rw0.w)
    BLEND_STEP(S1.x, rw1.x) BLEND_STEP(S1.y, rw1.y)
    BLEND_STEP(S1.z, rw1.z) BLEND_STEP(S1.w, rw1.w)
    su = qred16(su);
    ssu = qred16(ssu);
    const float muu = su * (1.f / D);
    const float varu = ssu * (1.f / D) - muu * muu;
    const float rsu = __builtin_amdgcn_rsqf(varu + LN_EPS);

    if (active) {
#define OUT_STEP(SM, GM, BM_) clipf(fmaf((SM - muu) * rsu, GM, BM_), -10.f, 10.f)
        float4 o0, o1;
        o0.x = OUT_STEP(S0.x, cgA.x, cbA.x); o0.y = OUT_STEP(S0.y, cgA.y, cbA.y);
        o0.z = OUT_STEP(S0.z, cgA.z, cbA.z); o0.w = OUT_STEP(S0.w, cgA.w, cbA.w);
        o1.x = OUT_STEP(S1.x, cgB.x, cbB.x); o1.y = OUT_STEP(S1.y, cgB.y, cbB.y);
        o1.z = OUT_STEP(S1.z, cgB.z, cbB.z); o1.w = OUT_STEP(S1.w, cgB.w, cbB.w);
        *(float4*)(out + (size_t)b * D + 4 * q) = o0;
        *(float4*)(out + (size_t)b * D + 64 + 4 * q) = o1;
    }
}

extern "C" void kernel_launch(void* const* d_in, const int* in_sizes, int n_in,
                              void* d_out, int out_size, void* d_ws, size_t ws_size,
                              hipStream_t stream) {
    const int*   nids = (const int*)d_in[0];
    const float* ef   = (const float*)d_in[1];
    const float* t    = (const float*)d_in[2];
    const float* raw  = (const float*)d_in[3];
    const float* prot = (const float*)d_in[4];
    const float* pg   = (const float*)d_in[5];
    const float* pb   = (const float*)d_in[6];
    const float* tw   = (const float*)d_in[7];
    const float* tb   = (const float*)d_in[8];
    const float* ew   = (const float*)d_in[9];
    const float* eb   = (const float*)d_in[10];
    const float* qw   = (const float*)d_in[11];
    const float* qb   = (const float*)d_in[12];
    const float* cg   = (const float*)d_in[13];
    const float* cb   = (const float*)d_in[14];
    const float* gw   = (const float*)d_in[15];
    const float* gb   = (const float*)d_in[16];
    const float* temp = (const float*)d_in[17];
    float* ws  = (float*)d_ws;
    float* out = (float*)d_out;
    const int Btot = in_sizes[0];

    hipLaunchKernelGGL(k0_fold, dim3(258), dim3(128), 0, stream,
                       qw, qb, ew, eb, pg, pb, ws);
    hipLaunchKernelGGL(k_gemm, dim3((Btot + BM - 1) / BM), dim3(256), 0, stream,
                       nids, ef, t, raw, tw, tb, ws, out, Btot);
    hipLaunchKernelGGL(k_epi, dim3((Btot + EPB - 1) / EPB), dim3(256), 0, stream,
                       nids, t, raw, prot, pg, pb, tw, tb, cg, cb, gw, gb, temp, ws, out, Btot);
}

// Round 6
// 212.915 us; speedup vs baseline: 3.0316x; 1.0206x over previous
//
#include <hip/hip_runtime.h>

#define D 128
#define EDIM 64
#define TDIM 64
#define KTOT 256
#define CHUNK 32
#define NCH 8
#define NP 5
#define BM 64      // elements per block, GEMM kernel
#define EPB 16     // elements per block, epilogue kernel
#define LN_EPS 1e-4f

typedef float v2f __attribute__((ext_vector_type(2)));
typedef float v4f __attribute__((ext_vector_type(4)));

__device__ __forceinline__ float clipf(float x, float lo, float hi) {
    return fminf(fmaxf(x, lo), hi);
}

// packed dual-FMA: a.lo += w.lo*v.lo ; a.hi += w.hi*v.hi
__device__ __forceinline__ void pkfma(v2f& a, v2f w, v2f v) {
    asm("v_pk_fma_f32 %0, %1, %2, %0" : "+v"(a) : "v"(w), "v"(v));
}

// reduction across the 16 lanes owning one element — pure-VALU DPP version.
// quad_perm xor1, xor2 give quad sums; row_ror:4, row_ror:8 combine quads.
template <int CTRL>
__device__ __forceinline__ float dpp_addstep(float v) {
    int o = __builtin_amdgcn_update_dpp(0, __float_as_int(v), CTRL, 0xF, 0xF, true);
    return v + __int_as_float(o);
}
__device__ __forceinline__ float qred16(float v) {
    v = dpp_addstep<0xB1>(v);    // quad_perm [1,0,3,2]  (xor 1)
    v = dpp_addstep<0x4E>(v);    // quad_perm [2,3,0,1]  (xor 2)
    v = dpp_addstep<0x124>(v);   // row_ror:4
    v = dpp_addstep<0x128>(v);   // row_ror:8
    return v;
}

#define AXPY4(ACC, S, V) \
    ACC.x = fmaf(S, V.x, ACC.x); ACC.y = fmaf(S, V.y, ACC.y); \
    ACC.z = fmaf(S, V.z, ACC.z); ACC.w = fmaf(S, V.w, ACC.w);

#define DOT4(ACC, X, Y) \
    ACC = fmaf(X.x, Y.x, ACC); ACC = fmaf(X.y, Y.y, ACC); \
    ACC = fmaf(X.z, Y.z, ACC); ACC = fmaf(X.w, Y.w, ACC);

#define SQ4(ACC, X) \
    ACC = fmaf(X.x, X.x, ACC); ACC = fmaf(X.y, X.y, ACC); \
    ACC = fmaf(X.z, X.z, ACC); ACC = fmaf(X.w, X.w, ACC);

// ---------------- K0: fold weights into ws ----------------
// ws layout (floats): Wt[256*128] (k-major: Wt[k][d]), c0[128], cc[3]={sgg,sgb,sbb}
__global__ void k0_fold(const float* __restrict__ qw, const float* __restrict__ qb,
                        const float* __restrict__ ew, const float* __restrict__ eb,
                        const float* __restrict__ pg, const float* __restrict__ pb,
                        float* __restrict__ ws) {
    const int d = threadIdx.x;   // 0..127
    const int bk = blockIdx.x;   // 0..257
    float* Wt = ws;
    float* c0 = ws + KTOT * D;
    float* cc = c0 + D;
    if (bk < 128) {
        Wt[bk * D + d] = qw[d * 320 + bk];
    } else if (bk < 192) {
        const int e = bk - 128;
        const float4* qrow = (const float4*)(qw + d * 320 + 128);
        float s = 0.f;
        #pragma unroll
        for (int g = 0; g < 32; ++g) {
            float4 q = qrow[g];
            s = fmaf(q.x, ew[(4 * g + 0) * EDIM + e], s);
            s = fmaf(q.y, ew[(4 * g + 1) * EDIM + e], s);
            s = fmaf(q.z, ew[(4 * g + 2) * EDIM + e], s);
            s = fmaf(q.w, ew[(4 * g + 3) * EDIM + e], s);
        }
        Wt[bk * D + d] = s;
    } else if (bk < 256) {
        Wt[bk * D + d] = qw[d * 320 + 256 + (bk - 192)];
    } else if (bk == 256) {
        const float4* qrow = (const float4*)(qw + d * 320 + 128);
        const float4* eb4 = (const float4*)eb;
        float s = qb[d];
        #pragma unroll
        for (int g = 0; g < 32; ++g) {
            float4 q = qrow[g], e4 = eb4[g];
            s = fmaf(q.x, e4.x, s); s = fmaf(q.y, e4.y, s);
            s = fmaf(q.z, e4.z, s); s = fmaf(q.w, e4.w, s);
        }
        c0[d] = s;
    } else {
        if (d == 0) { float s = 0.f; for (int i = 0; i < D; ++i) s = fmaf(pg[i], pg[i], s); cc[0] = s; }
        if (d == 1) { float s = 0.f; for (int i = 0; i < D; ++i) s = fmaf(pg[i], pb[i], s); cc[1] = s; }
        if (d == 2) { float s = 0.f; for (int i = 0; i < D; ++i) s = fmaf(pb[i], pb[i], s); cc[2] = s; }
    }
}

// ---------------- K_gemm: q_pre = W' @ [raw, ef, te] + c0 ----------------
// 64 elems/block; thread (dg = tid&15, eg = tid>>4) computes elems eg*4..eg*4+3
// at dims [4dg..4dg+3] and [64+4dg..64+4dg+3]. Register double-buffered staging;
// inner loop uses v_pk_fma_f32 (packed dual f32 FMA).
__global__ __launch_bounds__(256, 4)
void k_gemm(const int* __restrict__ nids, const float* __restrict__ ef,
            const float* __restrict__ tarr, const float* __restrict__ raw_mem,
            const float* __restrict__ tw, const float* __restrict__ tb,
            const float* __restrict__ ws, float* qpre, int Btot) {
    __shared__ v4f   Wb[CHUNK * 32];       // 16 KB: [k][32 float4]
    __shared__ float Vb[BM][CHUNK + 1];    // 8.25 KB
    __shared__ float tvals[BM];

    const int tid = threadIdx.x;
    const int dg = tid & 15;
    const int eg = tid >> 4;
    const int b0 = blockIdx.x * BM;

    if (tid < BM) tvals[tid] = tarr[min(b0 + tid, Btot - 1)];

    // acc as 8 v2f pairs per element slot: [j][0]=(4dg,4dg+1) [1]=(+2,+3) [2]=(64+4dg,..) [3]
    const v4f* c04 = (const v4f*)(ws + KTOT * D);
    const v4f cA = c04[dg], cB = c04[16 + dg];
    v2f acc2[4][4];
    #pragma unroll
    for (int j = 0; j < 4; ++j) {
        acc2[j][0] = __builtin_shufflevector(cA, cA, 0, 1);
        acc2[j][1] = __builtin_shufflevector(cA, cA, 2, 3);
        acc2[j][2] = __builtin_shufflevector(cB, cB, 0, 1);
        acc2[j][3] = __builtin_shufflevector(cB, cB, 2, 3);
    }

    const int m = tid >> 2;   // staged element 0..63
    const int i4 = tid & 3;   // quarter of its 32 k-values
    const int sb = min(b0 + m, Btot - 1);
    const float* rawrow = raw_mem + (size_t)nids[sb] * D;
    const float* efrow = ef + (size_t)sb * EDIM;

    // ---- prefetch chunk 0 into registers ----
    v4f w0r, w1r, w2r, w3r, x0, x1;
    {
        const v4f* wsrc = (const v4f*)ws;
        w0r = wsrc[tid]; w1r = wsrc[tid + 256]; w2r = wsrc[tid + 512]; w3r = wsrc[tid + 768];
        const v4f* src = (const v4f*)rawrow;
        x0 = src[i4 * 2]; x1 = src[i4 * 2 + 1];
    }

    #pragma unroll 1
    for (int c = 0; c < NCH; ++c) {
        __syncthreads();   // previous compute done; LDS reusable
        Wb[tid] = w0r; Wb[tid + 256] = w1r; Wb[tid + 512] = w2r; Wb[tid + 768] = w3r;
        {
            float* vd = &Vb[m][i4 * 8];
            vd[0] = x0[0]; vd[1] = x0[1]; vd[2] = x0[2]; vd[3] = x0[3];
            vd[4] = x1[0]; vd[5] = x1[1]; vd[6] = x1[2]; vd[7] = x1[3];
        }
        __syncthreads();   // LDS ready
        // ---- prefetch chunk c+1 (global latency hides under compute below) ----
        if (c < NCH - 1) {
            const v4f* wsrc = (const v4f*)(ws + (size_t)(c + 1) * CHUNK * D);
            w0r = wsrc[tid]; w1r = wsrc[tid + 256]; w2r = wsrc[tid + 512]; w3r = wsrc[tid + 768];
            const int cn = c + 1;
            if (cn < 4) {
                const v4f* src = (const v4f*)(rawrow + cn * CHUNK);
                x0 = src[i4 * 2]; x1 = src[i4 * 2 + 1];
            } else if (cn < 6) {
                const v4f* src = (const v4f*)(efrow + (cn - 4) * CHUNK);
                x0 = src[i4 * 2]; x1 = src[i4 * 2 + 1];
            } else {
                const float tv = tvals[m];
                const int u0 = (cn - 6) * CHUNK + i4 * 8;
                #pragma unroll
                for (int jj = 0; jj < 4; ++jj) x0[jj] = __cosf(fmaf(tv, tw[u0 + jj], tb[u0 + jj]));
                #pragma unroll
                for (int jj = 0; jj < 4; ++jj) x1[jj] = __cosf(fmaf(tv, tw[u0 + 4 + jj], tb[u0 + 4 + jj]));
            }
        }
        // ---- compute chunk c ----
        #pragma unroll
        for (int k = 0; k < CHUNK; ++k) {
            const v4f w0 = Wb[k * 32 + dg];
            const v4f w1 = Wb[k * 32 + 16 + dg];
            const v2f w0lo = __builtin_shufflevector(w0, w0, 0, 1);
            const v2f w0hi = __builtin_shufflevector(w0, w0, 2, 3);
            const v2f w1lo = __builtin_shufflevector(w1, w1, 0, 1);
            const v2f w1hi = __builtin_shufflevector(w1, w1, 2, 3);
            #pragma unroll
            for (int j = 0; j < 4; ++j) {
                const float vk = Vb[eg * 4 + j][k];
                const v2f vv = {vk, vk};
                pkfma(acc2[j][0], w0lo, vv);
                pkfma(acc2[j][1], w0hi, vv);
                pkfma(acc2[j][2], w1lo, vv);
                pkfma(acc2[j][3], w1hi, vv);
            }
        }
    }

    #pragma unroll
    for (int j = 0; j < 4; ++j) {
        const int e = b0 + eg * 4 + j;
        if (e < Btot) {
            v4f oA, oB;
            oA[0] = acc2[j][0][0]; oA[1] = acc2[j][0][1]; oA[2] = acc2[j][1][0]; oA[3] = acc2[j][1][1];
            oB[0] = acc2[j][2][0]; oB[1] = acc2[j][2][1]; oB[2] = acc2[j][3][0]; oB[3] = acc2[j][3][1];
            *(v4f*)(qpre + (size_t)e * D + 4 * dg)      = oA;
            *(v4f*)(qpre + (size_t)e * D + 64 + 4 * dg) = oB;
        }
    }
}

// ---------------- K_epi: everything after q_pre; 16 lanes/elem ----------------
// qpre aliases out (read early, written late, same element -> safe).
__global__ __launch_bounds__(256, 4)
void k_epi(const int* __restrict__ nids, const float* __restrict__ tarr,
           const float* __restrict__ raw_mem, const float* __restrict__ protos,
           const float* __restrict__ pg, const float* __restrict__ pb,
           const float* __restrict__ tw, const float* __restrict__ tb,
           const float* __restrict__ cg, const float* __restrict__ cb,
           const float* __restrict__ gw, const float* __restrict__ gb,
           const float* __restrict__ temp, const float* __restrict__ ws,
           float* out, int Btot) {
    const int tid = threadIdx.x;
    const int q = tid & 15;
    const int e = tid >> 4;
    const int b = blockIdx.x * EPB + e;
    const bool active = (b < Btot);
    const int bb = active ? b : (Btot - 1);

    const int nid = nids[bb];
    const float* rawrow = raw_mem + (size_t)nid * D;
    const float* prow = protos + (size_t)nid * (NP * D);

    // q_pre (from out buffer), raw, protos -> registers
    float4 acc0 = *(const float4*)(out + (size_t)bb * D + 4 * q);
    float4 acc1 = *(const float4*)(out + (size_t)bb * D + 64 + 4 * q);
    const float4 rw0 = *(const float4*)(rawrow + 4 * q);
    const float4 rw1 = *(const float4*)(rawrow + 64 + 4 * q);
    float4 px[NP][2];
    #pragma unroll
    for (int p = 0; p < NP; ++p) {
        px[p][0] = *(const float4*)(prow + p * D + 4 * q);
        px[p][1] = *(const float4*)(prow + p * D + 64 + 4 * q);
    }

    // ---- gate partials: raw and te shares ----
    float gsum = 0.f;
    {
        const float4 g0 = *(const float4*)(gw + 4 * q);
        const float4 g1 = *(const float4*)(gw + 64 + 4 * q);
        gsum = fmaf(g0.x, clipf(rw0.x, -100.f, 100.f), gsum);
        gsum = fmaf(g0.y, clipf(rw0.y, -100.f, 100.f), gsum);
        gsum = fmaf(g0.z, clipf(rw0.z, -100.f, 100.f), gsum);
        gsum = fmaf(g0.w, clipf(rw0.w, -100.f, 100.f), gsum);
        gsum = fmaf(g1.x, clipf(rw1.x, -100.f, 100.f), gsum);
        gsum = fmaf(g1.y, clipf(rw1.y, -100.f, 100.f), gsum);
        gsum = fmaf(g1.z, clipf(rw1.z, -100.f, 100.f), gsum);
        gsum = fmaf(g1.w, clipf(rw1.w, -100.f, 100.f), gsum);
        const float tval = tarr[bb];
        const float4 tw4 = *(const float4*)(tw + 4 * q);
        const float4 tb4 = *(const float4*)(tb + 4 * q);
        const float4 gt = *(const float4*)(gw + 2 * D + 4 * q);
        gsum = fmaf(gt.x, __cosf(fmaf(tval, tw4.x, tb4.x)), gsum);
        gsum = fmaf(gt.y, __cosf(fmaf(tval, tw4.y, tb4.y)), gsum);
        gsum = fmaf(gt.z, __cosf(fmaf(tval, tw4.z, tb4.z)), gsum);
        gsum = fmaf(gt.w, __cosf(fmaf(tval, tw4.w, tb4.w)), gsum);
    }

    // ---- query = tanh(LN(q_pre)) ----
    float sx = (acc0.x + acc0.y) + (acc0.z + acc0.w) + (acc1.x + acc1.y) + (acc1.z + acc1.w);
    sx = qred16(sx);
    const float mu = sx * (1.f / D);
    float sv = 0.f;
    {
        float a;
        a = acc0.x - mu; sv = fmaf(a, a, sv);
        a = acc0.y - mu; sv = fmaf(a, a, sv);
        a = acc0.z - mu; sv = fmaf(a, a, sv);
        a = acc0.w - mu; sv = fmaf(a, a, sv);
        a = acc1.x - mu; sv = fmaf(a, a, sv);
        a = acc1.y - mu; sv = fmaf(a, a, sv);
        a = acc1.z - mu; sv = fmaf(a, a, sv);
        a = acc1.w - mu; sv = fmaf(a, a, sv);
    }
    sv = qred16(sv);
    const float rsq = __builtin_amdgcn_rsqf(sv * (1.f / D) + LN_EPS);

    const float4 cgA = *(const float4*)(cg + 4 * q);
    const float4 cgB = *(const float4*)(cg + 64 + 4 * q);
    const float4 cbA = *(const float4*)(cb + 4 * q);
    const float4 cbB = *(const float4*)(cb + 64 + 4 * q);

    float ssq = 0.f;
#define TANH_STEP(AM, GM, BM_) { \
        float x_ = fmaf((AM - mu) * rsq, GM, BM_); \
        float e_ = __expf(2.f * x_); \
        AM = 1.f - 2.f * __builtin_amdgcn_rcpf(e_ + 1.f); \
        ssq = fmaf(AM, AM, ssq); }
    TANH_STEP(acc0.x, cgA.x, cbA.x) TANH_STEP(acc0.y, cgA.y, cbA.y)
    TANH_STEP(acc0.z, cgA.z, cbA.z) TANH_STEP(acc0.w, cgA.w, cbA.w)
    TANH_STEP(acc1.x, cgB.x, cbB.x) TANH_STEP(acc1.y, cgB.y, cbB.y)
    TANH_STEP(acc1.z, cgB.z, cbB.z) TANH_STEP(acc1.w, cgB.w, cbB.w)
    ssq = qred16(ssq);
    const float invq = __builtin_amdgcn_rcpf(fmaxf(sqrtf(ssq), 1e-6f));

    const float4 pgA = *(const float4*)(pg + 4 * q);
    const float4 pgB = *(const float4*)(pg + 64 + 4 * q);
    const float4 pbA = *(const float4*)(pb + 4 * q);
    const float4 pbB = *(const float4*)(pb + 64 + 4 * q);

    float aqg = 0.f, aqb = 0.f;
#define QG_STEP(AM, GM, BM_) { \
        float qn_ = AM * invq; \
        AM = qn_ * GM; \
        aqg += AM; \
        aqb = fmaf(qn_, BM_, aqb); }
    QG_STEP(acc0.x, pgA.x, pbA.x) QG_STEP(acc0.y, pgA.y, pbA.y)
    QG_STEP(acc0.z, pgA.z, pbA.z) QG_STEP(acc0.w, pgA.w, pbA.w)
    QG_STEP(acc1.x, pgB.x, pbB.x) QG_STEP(acc1.y, pgB.y, pbB.y)
    QG_STEP(acc1.z, pgB.z, pbB.z) QG_STEP(acc1.w, pgB.w, pbB.w)
    aqg = qred16(aqg);
    aqb = qred16(aqb);

    // ---- per-proto LN stats + cosine sim from register-resident px ----
    const float sbb = (ws + KTOT * D + D)[2];
    const float tempc = fminf(fmaxf(temp[0], 0.05f), 2.0f) + 1e-4f;
    const float its = 1.0f / tempc;
    float mups[NP], rsps[NP], simv[NP];
    #pragma unroll
    for (int p = 0; p < NP; ++p) {
        float s_x = (px[p][0].x + px[p][0].y) + (px[p][0].z + px[p][0].w)
                  + (px[p][1].x + px[p][1].y) + (px[p][1].z + px[p][1].w);
        float sxx = 0.f, sqgx = 0.f;
        SQ4(sxx, px[p][0]) SQ4(sxx, px[p][1])
        DOT4(sqgx, acc0, px[p][0]) DOT4(sqgx, acc1, px[p][1])
        s_x = qred16(s_x); sxx = qred16(sxx); sqgx = qred16(sqgx);
        const float mup = s_x * (1.f / D);
        const float varp = sxx * (1.f / D) - mup * mup;
        const float rsp = __builtin_amdgcn_rsqf(varp + LN_EPS);
        float sz2 = 0.f, szb = 0.f;
#define ZSTEP(XM, GM, BM_) { \
        float z_ = (XM - mup) * GM; \
        sz2 = fmaf(z_, z_, sz2); \
        szb = fmaf(z_, BM_, szb); }
        ZSTEP(px[p][0].x, pgA.x, pbA.x) ZSTEP(px[p][0].y, pgA.y, pbA.y)
        ZSTEP(px[p][0].z, pgA.z, pbA.z) ZSTEP(px[p][0].w, pgA.w, pbA.w)
        ZSTEP(px[p][1].x, pgB.x, pbB.x) ZSTEP(px[p][1].y, pgB.y, pbB.y)
        ZSTEP(px[p][1].z, pgB.z, pbB.z) ZSTEP(px[p][1].w, pgB.w, pbB.w)
        sz2 = qred16(sz2); szb = qred16(szb);
        const float dot = fmaf(rsp, sqgx - mup * aqg, aqb);
        float nrm2 = fmaf(rsp * rsp, sz2, fmaf(2.f * rsp, szb, sbb));
        nrm2 = fmaxf(nrm2, 0.f);
        const float inv = __builtin_amdgcn_rcpf(fmaxf(sqrtf(nrm2), 1e-6f));
        mups[p] = mup;
        rsps[p] = rsp;
        simv[p] = clipf(dot * inv, -30.f, 30.f) * its;
    }

    // ---- softmax over 5 (redundant per lane) ----
    float mx = fmaxf(fmaxf(fmaxf(simv[0], simv[1]), fmaxf(simv[2], simv[3])), simv[4]);
    float wp[NP];
    float Z = 0.f;
    #pragma unroll
    for (int p = 0; p < NP; ++p) { float ev = __expf(simv[p] - mx); wp[p] = ev; Z += ev; }
    const float iZ = 1.f / Z;
    float a0 = 0.f, a1 = 0.f;
    #pragma unroll
    for (int p = 0; p < NP; ++p) {
        float at = wp[p] * iZ;
        a0 += at;
        float w = at * rsps[p];
        a1 = fmaf(w, mups[p], a1);
        wp[p] = w;
    }

    // ---- weighted proto sum from registers ----
    float4 S0 = make_float4(0.f, 0.f, 0.f, 0.f);
    float4 S1 = make_float4(0.f, 0.f, 0.f, 0.f);
    #pragma unroll
    for (int p = 0; p < NP; ++p) {
        AXPY4(S0, wp[p], px[p][0]);
        AXPY4(S1, wp[p], px[p][1]);
    }

    // ---- cand + gate contribution ----
    const float4 gc0 = *(const float4*)(gw + D + 4 * q);
    const float4 gc1 = *(const float4*)(gw + D + 64 + 4 * q);
#define CAND_STEP(SM, GM, BM_, GWm) { \
        SM = clipf(fmaf(GM, SM - a1, BM_ * a0), -5.f, 5.f); \
        gsum = fmaf(GWm, SM, gsum); }
    CAND_STEP(S0.x, pgA.x, pbA.x, gc0.x) CAND_STEP(S0.y, pgA.y, pbA.y, gc0.y)
    CAND_STEP(S0.z, pgA.z, pbA.z, gc0.z) CAND_STEP(S0.w, pgA.w, pbA.w, gc0.w)
    CAND_STEP(S1.x, pgB.x, pbB.x, gc1.x) CAND_STEP(S1.y, pgB.y, pbB.y, gc1.y)
    CAND_STEP(S1.z, pgB.z, pbB.z, gc1.z) CAND_STEP(S1.w, pgB.w, pbB.w, gc1.w)
    gsum = qred16(gsum);
    const float gpre = gsum + gb[0];
    const float gate = __builtin_amdgcn_rcpf(1.f + __expf(-gpre));

    // ---- upd = raw + gate*(cand - raw); LN; clip; store ----
    float su = 0.f, ssu = 0.f;
#define BLEND_STEP(SM, RM) { \
        SM = fmaf(gate, SM - RM, RM); \
        su += SM; \
        ssu = fmaf(SM, SM, ssu); }
    BLEND_STEP(S0.x, rw0.x) BLEND_STEP(S0.y, rw0.y)
    BLEND_STEP(S0.z, rw0.z) BLEND_STEP(S0.w, rw0.w)
    BLEND_STEP(S1.x, rw1.x) BLEND_STEP(S1.y, rw1.y)
    BLEND_STEP(S1.z, rw1.z) BLEND_STEP(S1.w, rw1.w)
    su = qred16(su);
    ssu = qred16(ssu);
    const float muu = su * (1.f / D);
    const float varu = ssu * (1.f / D) - muu * muu;
    const float rsu = __builtin_amdgcn_rsqf(varu + LN_EPS);

    if (active) {
#define OUT_STEP(SM, GM, BM_) clipf(fmaf((SM - muu) * rsu, GM, BM_), -10.f, 10.f)
        float4 o0, o1;
        o0.x = OUT_STEP(S0.x, cgA.x, cbA.x); o0.y = OUT_STEP(S0.y, cgA.y, cbA.y);
        o0.z = OUT_STEP(S0.z, cgA.z, cbA.z); o0.w = OUT_STEP(S0.w, cgA.w, cbA.w);
        o1.x = OUT_STEP(S1.x, cgB.x, cbB.x); o1.y = OUT_STEP(S1.y, cgB.y, cbB.y);
        o1.z = OUT_STEP(S1.z, cgB.z, cbB.z); o1.w = OUT_STEP(S1.w, cgB.w, cbB.w);
        *(float4*)(out + (size_t)b * D + 4 * q) = o0;
        *(float4*)(out + (size_t)b * D + 64 + 4 * q) = o1;
    }
}

extern "C" void kernel_launch(void* const* d_in, const int* in_sizes, int n_in,
                              void* d_out, int out_size, void* d_ws, size_t ws_size,
                              hipStream_t stream) {
    const int*   nids = (const int*)d_in[0];
    const float* ef   = (const float*)d_in[1];
    const float* t    = (const float*)d_in[2];
    const float* raw  = (const float*)d_in[3];
    const float* prot = (const float*)d_in[4];
    const float* pg   = (const float*)d_in[5];
    const float* pb   = (const float*)d_in[6];
    const float* tw   = (const float*)d_in[7];
    const float* tb   = (const float*)d_in[8];
    const float* ew   = (const float*)d_in[9];
    const float* eb   = (const float*)d_in[10];
    const float* qw   = (const float*)d_in[11];
    const float* qb   = (const float*)d_in[12];
    const float* cg   = (const float*)d_in[13];
    const float* cb   = (const float*)d_in[14];
    const float* gw   = (const float*)d_in[15];
    const float* gb   = (const float*)d_in[16];
    const float* temp = (const float*)d_in[17];
    float* ws  = (float*)d_ws;
    float* out = (float*)d_out;
    const int Btot = in_sizes[0];

    hipLaunchKernelGGL(k0_fold, dim3(258), dim3(128), 0, stream,
                       qw, qb, ew, eb, pg, pb, ws);
    hipLaunchKernelGGL(k_gemm, dim3((Btot + BM - 1) / BM), dim3(256), 0, stream,
                       nids, ef, t, raw, tw, tb, ws, out, Btot);
    hipLaunchKernelGGL(k_epi, dim3((Btot + EPB - 1) / EPB), dim3(256), 0, stream,
                       nids, t, raw, prot, pg, pb, tw, tb, cg, cb, gw, gb, temp, ws, out, Btot);
}

// Round 7
// 150.923 us; speedup vs baseline: 4.2768x; 1.4107x over previous
//
#include <hip/hip_runtime.h>

#define D 128
#define EDIM 64
#define TDIM 64
#define KTOT 256
#define NP 5
#define EPB 16     // elements per block, epilogue kernel
#define LN_EPS 1e-4f
#define WSB_OFF 33024   // float offset of bf16 B-fragments in ws

typedef float v4f __attribute__((ext_vector_type(4)));
typedef float f32x4 __attribute__((ext_vector_type(4)));
typedef short bf16x8 __attribute__((ext_vector_type(8)));

__device__ __forceinline__ float clipf(float x, float lo, float hi) {
    return fminf(fmaxf(x, lo), hi);
}

__device__ __forceinline__ unsigned short bf16rne(float x) {
    unsigned int u = __float_as_uint(x);
    unsigned int r = (u + 0x7fffu + ((u >> 16) & 1u)) >> 16;
    return (unsigned short)r;
}
__device__ __forceinline__ float bf16tof(unsigned short h) {
    return __uint_as_float(((unsigned int)h) << 16);
}

// reduction across the 16 lanes owning one element — pure-VALU DPP.
template <int CTRL>
__device__ __forceinline__ float dpp_addstep(float v) {
    int o = __builtin_amdgcn_update_dpp(0, __float_as_int(v), CTRL, 0xF, 0xF, true);
    return v + __int_as_float(o);
}
__device__ __forceinline__ float qred16(float v) {
    v = dpp_addstep<0xB1>(v);    // quad_perm xor 1
    v = dpp_addstep<0x4E>(v);    // quad_perm xor 2
    v = dpp_addstep<0x124>(v);   // row_ror:4
    v = dpp_addstep<0x128>(v);   // row_ror:8
    return v;
}

#define AXPY4(ACC, S, V) \
    ACC.x = fmaf(S, V.x, ACC.x); ACC.y = fmaf(S, V.y, ACC.y); \
    ACC.z = fmaf(S, V.z, ACC.z); ACC.w = fmaf(S, V.w, ACC.w);

#define DOT4(ACC, X, Y) \
    ACC = fmaf(X.x, Y.x, ACC); ACC = fmaf(X.y, Y.y, ACC); \
    ACC = fmaf(X.z, Y.z, ACC); ACC = fmaf(X.w, Y.w, ACC);

#define SQ4(ACC, X) \
    ACC = fmaf(X.x, X.x, ACC); ACC = fmaf(X.y, X.y, ACC); \
    ACC = fmaf(X.z, X.z, ACC); ACC = fmaf(X.w, X.w, ACC);

// ---------------- K0: fold weights into ws ----------------
// ws layout (floats): Wt[256*128] (k-major), c0[128], cc[3]={sgg,sgb,sbb},
// then at WSB_OFF: bf16x8 B-fragments [kb(8)][nt(8)][s(2)][lane(64)].
__global__ void k0_fold(const float* __restrict__ qw, const float* __restrict__ qb,
                        const float* __restrict__ ew, const float* __restrict__ eb,
                        const float* __restrict__ pg, const float* __restrict__ pb,
                        float* __restrict__ ws) {
    const int d = threadIdx.x;   // 0..127
    const int bk = blockIdx.x;   // 0..257
    float* Wt = ws;
    float* c0 = ws + KTOT * D;
    float* cc = c0 + D;
    if (bk < 128) {
        Wt[bk * D + d] = qw[d * 320 + bk];
    } else if (bk < 192) {
        const int e = bk - 128;
        const float4* qrow = (const float4*)(qw + d * 320 + 128);
        float s = 0.f;
        #pragma unroll
        for (int g = 0; g < 32; ++g) {
            float4 q = qrow[g];
            s = fmaf(q.x, ew[(4 * g + 0) * EDIM + e], s);
            s = fmaf(q.y, ew[(4 * g + 1) * EDIM + e], s);
            s = fmaf(q.z, ew[(4 * g + 2) * EDIM + e], s);
            s = fmaf(q.w, ew[(4 * g + 3) * EDIM + e], s);
        }
        Wt[bk * D + d] = s;
    } else if (bk < 256) {
        Wt[bk * D + d] = qw[d * 320 + 256 + (bk - 192)];
    } else if (bk == 256) {
        const float4* qrow = (const float4*)(qw + d * 320 + 128);
        const float4* eb4 = (const float4*)eb;
        float s = qb[d];
        #pragma unroll
        for (int g = 0; g < 32; ++g) {
            float4 q = qrow[g], e4 = eb4[g];
            s = fmaf(q.x, e4.x, s); s = fmaf(q.y, e4.y, s);
            s = fmaf(q.z, e4.z, s); s = fmaf(q.w, e4.w, s);
        }
        c0[d] = s;
    } else {
        if (d == 0) { float s = 0.f; for (int i = 0; i < D; ++i) s = fmaf(pg[i], pg[i], s); cc[0] = s; }
        if (d == 1) { float s = 0.f; for (int i = 0; i < D; ++i) s = fmaf(pg[i], pb[i], s); cc[1] = s; }
        if (d == 2) { float s = 0.f; for (int i = 0; i < D; ++i) s = fmaf(pb[i], pb[i], s); cc[2] = s; }
    }
}

// ---------------- K0b: pack Wt into split-bf16 MFMA B-fragments ----------------
// B[k][col]: lane l holds k = kb*32 + (l>>4)*8 + j, col = nt*16 + (l&15).
__global__ void k0b_pack(float* __restrict__ ws) {
    const int kb = blockIdx.x >> 3;
    const int nt = blockIdx.x & 7;
    const int l = threadIdx.x;    // 0..63
    const float* Wt = ws;
    const int col = nt * 16 + (l & 15);
    const int kbase = kb * 32 + (l >> 4) * 8;
    bf16x8 hi, lo;
    #pragma unroll
    for (int j = 0; j < 8; ++j) {
        float x = Wt[(kbase + j) * D + col];
        unsigned short h = bf16rne(x);
        hi[j] = (short)h;
        lo[j] = (short)bf16rne(x - bf16tof(h));
    }
    bf16x8* outp = (bf16x8*)(ws + WSB_OFF);
    outp[((kb * 8 + nt) * 2 + 0) * 64 + l] = hi;
    outp[((kb * 8 + nt) * 2 + 1) * 64 + l] = lo;
}

// ---------------- K_mfma: q_pre = W' @ [raw, ef, te] + c0 via split-bf16 MFMA ----
// 4 waves/block, each wave one 16-elem m-tile, all 8 n-tiles, K=256 (8 k-blocks).
// A: row = lane&15, k = kb*32 + (lane>>4)*8 + j  (same k convention as k0b pack).
// C: col = lane&15, row = (lane>>4)*4 + reg  [m89-verified].
__global__ __launch_bounds__(256, 2)
void k_mfma(const int* __restrict__ nids, const float* __restrict__ ef,
            const float* __restrict__ tarr, const float* __restrict__ raw_mem,
            const float* __restrict__ tw, const float* __restrict__ tb,
            const float* __restrict__ ws, float* __restrict__ qpre, int Btot) {
    const int tid = threadIdx.x;
    const int wave = tid >> 6;
    const int lane = tid & 63;
    const int m0 = blockIdx.x * 64 + wave * 16;
    const int row = lane & 15;
    const int kg = lane >> 4;

    const int elemA = min(m0 + row, Btot - 1);
    const int nid = nids[elemA];
    const float* rawp = raw_mem + (size_t)nid * D + kg * 8;
    const float* efp = ef + (size_t)elemA * EDIM + kg * 8;
    const float tval = tarr[elemA];

    const bf16x8* wb = (const bf16x8*)(ws + WSB_OFF);

    f32x4 acc[8];
    #pragma unroll
    for (int nt = 0; nt < 8; ++nt) acc[nt] = (f32x4){0.f, 0.f, 0.f, 0.f};

    #pragma unroll 1
    for (int kb = 0; kb < 8; ++kb) {
        // ---- load / compute this lane's 8 A-values (f32) ----
        float xs[8];
        if (kb < 4) {
            v4f a = *(const v4f*)(rawp + kb * 32);
            v4f b = *(const v4f*)(rawp + kb * 32 + 4);
            xs[0] = a[0]; xs[1] = a[1]; xs[2] = a[2]; xs[3] = a[3];
            xs[4] = b[0]; xs[5] = b[1]; xs[6] = b[2]; xs[7] = b[3];
        } else if (kb < 6) {
            v4f a = *(const v4f*)(efp + (kb - 4) * 32);
            v4f b = *(const v4f*)(efp + (kb - 4) * 32 + 4);
            xs[0] = a[0]; xs[1] = a[1]; xs[2] = a[2]; xs[3] = a[3];
            xs[4] = b[0]; xs[5] = b[1]; xs[6] = b[2]; xs[7] = b[3];
        } else {
            const int u0 = (kb - 6) * 32 + kg * 8;
            v4f wa = *(const v4f*)(tw + u0);
            v4f wbv = *(const v4f*)(tw + u0 + 4);
            v4f ba = *(const v4f*)(tb + u0);
            v4f bbv = *(const v4f*)(tb + u0 + 4);
            xs[0] = __cosf(fmaf(tval, wa[0], ba[0]));
            xs[1] = __cosf(fmaf(tval, wa[1], ba[1]));
            xs[2] = __cosf(fmaf(tval, wa[2], ba[2]));
            xs[3] = __cosf(fmaf(tval, wa[3], ba[3]));
            xs[4] = __cosf(fmaf(tval, wbv[0], bbv[0]));
            xs[5] = __cosf(fmaf(tval, wbv[1], bbv[1]));
            xs[6] = __cosf(fmaf(tval, wbv[2], bbv[2]));
            xs[7] = __cosf(fmaf(tval, wbv[3], bbv[3]));
        }
        // ---- split into hi/lo bf16 fragments ----
        bf16x8 ahi, alo;
        #pragma unroll
        for (int j = 0; j < 8; ++j) {
            unsigned short h = bf16rne(xs[j]);
            ahi[j] = (short)h;
            alo[j] = (short)bf16rne(xs[j] - bf16tof(h));
        }
        // ---- 8 n-tiles × 3 split MFMAs ----
        #pragma unroll
        for (int nt = 0; nt < 8; ++nt) {
            bf16x8 bhi = wb[((kb * 8 + nt) * 2 + 0) * 64 + lane];
            bf16x8 blo = wb[((kb * 8 + nt) * 2 + 1) * 64 + lane];
            acc[nt] = __builtin_amdgcn_mfma_f32_16x16x32_bf16(ahi, bhi, acc[nt], 0, 0, 0);
            acc[nt] = __builtin_amdgcn_mfma_f32_16x16x32_bf16(ahi, blo, acc[nt], 0, 0, 0);
            acc[nt] = __builtin_amdgcn_mfma_f32_16x16x32_bf16(alo, bhi, acc[nt], 0, 0, 0);
        }
    }

    // ---- add folded bias c0 and store: C row=(lane>>4)*4+r, col=lane&15 ----
    const float* c0 = ws + KTOT * D;
    const int col = lane & 15;
    float c0v[8];
    #pragma unroll
    for (int nt = 0; nt < 8; ++nt) c0v[nt] = c0[nt * 16 + col];
    #pragma unroll
    for (int r = 0; r < 4; ++r) {
        const int erow = m0 + kg * 4 + r;
        if (erow < Btot) {
            float* qp = qpre + (size_t)erow * D + col;
            #pragma unroll
            for (int nt = 0; nt < 8; ++nt) qp[nt * 16] = acc[nt][r] + c0v[nt];
        }
    }
}

// ---------------- K_epi: everything after q_pre; 16 lanes/elem ----------------
// qpre aliases out (read early, written late, same element -> safe).
__global__ __launch_bounds__(256, 4)
void k_epi(const int* __restrict__ nids, const float* __restrict__ tarr,
           const float* __restrict__ raw_mem, const float* __restrict__ protos,
           const float* __restrict__ pg, const float* __restrict__ pb,
           const float* __restrict__ tw, const float* __restrict__ tb,
           const float* __restrict__ cg, const float* __restrict__ cb,
           const float* __restrict__ gw, const float* __restrict__ gb,
           const float* __restrict__ temp, const float* __restrict__ ws,
           float* out, int Btot) {
    const int tid = threadIdx.x;
    const int q = tid & 15;
    const int e = tid >> 4;
    const int b = blockIdx.x * EPB + e;
    const bool active = (b < Btot);
    const int bb = active ? b : (Btot - 1);

    const int nid = nids[bb];
    const float* rawrow = raw_mem + (size_t)nid * D;
    const float* prow = protos + (size_t)nid * (NP * D);

    float4 acc0 = *(const float4*)(out + (size_t)bb * D + 4 * q);
    float4 acc1 = *(const float4*)(out + (size_t)bb * D + 64 + 4 * q);
    const float4 rw0 = *(const float4*)(rawrow + 4 * q);
    const float4 rw1 = *(const float4*)(rawrow + 64 + 4 * q);
    float4 px[NP][2];
    #pragma unroll
    for (int p = 0; p < NP; ++p) {
        px[p][0] = *(const float4*)(prow + p * D + 4 * q);
        px[p][1] = *(const float4*)(prow + p * D + 64 + 4 * q);
    }

    float gsum = 0.f;
    {
        const float4 g0 = *(const float4*)(gw + 4 * q);
        const float4 g1 = *(const float4*)(gw + 64 + 4 * q);
        gsum = fmaf(g0.x, clipf(rw0.x, -100.f, 100.f), gsum);
        gsum = fmaf(g0.y, clipf(rw0.y, -100.f, 100.f), gsum);
        gsum = fmaf(g0.z, clipf(rw0.z, -100.f, 100.f), gsum);
        gsum = fmaf(g0.w, clipf(rw0.w, -100.f, 100.f), gsum);
        gsum = fmaf(g1.x, clipf(rw1.x, -100.f, 100.f), gsum);
        gsum = fmaf(g1.y, clipf(rw1.y, -100.f, 100.f), gsum);
        gsum = fmaf(g1.z, clipf(rw1.z, -100.f, 100.f), gsum);
        gsum = fmaf(g1.w, clipf(rw1.w, -100.f, 100.f), gsum);
        const float tval = tarr[bb];
        const float4 tw4 = *(const float4*)(tw + 4 * q);
        const float4 tb4 = *(const float4*)(tb + 4 * q);
        const float4 gt = *(const float4*)(gw + 2 * D + 4 * q);
        gsum = fmaf(gt.x, __cosf(fmaf(tval, tw4.x, tb4.x)), gsum);
        gsum = fmaf(gt.y, __cosf(fmaf(tval, tw4.y, tb4.y)), gsum);
        gsum = fmaf(gt.z, __cosf(fmaf(tval, tw4.z, tb4.z)), gsum);
        gsum = fmaf(gt.w, __cosf(fmaf(tval, tw4.w, tb4.w)), gsum);
    }

    // ---- query = tanh(LN(q_pre)) ----
    float sx = (acc0.x + acc0.y) + (acc0.z + acc0.w) + (acc1.x + acc1.y) + (acc1.z + acc1.w);
    sx = qred16(sx);
    const float mu = sx * (1.f / D);
    float sv = 0.f;
    {
        float a;
        a = acc0.x - mu; sv = fmaf(a, a, sv);
        a = acc0.y - mu; sv = fmaf(a, a, sv);
        a = acc0.z - mu; sv = fmaf(a, a, sv);
        a = acc0.w - mu; sv = fmaf(a, a, sv);
        a = acc1.x - mu; sv = fmaf(a, a, sv);
        a = acc1.y - mu; sv = fmaf(a, a, sv);
        a = acc1.z - mu; sv = fmaf(a, a, sv);
        a = acc1.w - mu; sv = fmaf(a, a, sv);
    }
    sv = qred16(sv);
    const float rsq = __builtin_amdgcn_rsqf(sv * (1.f / D) + LN_EPS);

    const float4 cgA = *(const float4*)(cg + 4 * q);
    const float4 cgB = *(const float4*)(cg + 64 + 4 * q);
    const float4 cbA = *(const float4*)(cb + 4 * q);
    const float4 cbB = *(const float4*)(cb + 64 + 4 * q);

    float ssq = 0.f;
#define TANH_STEP(AM, GM, BM_) { \
        float x_ = fmaf((AM - mu) * rsq, GM, BM_); \
        float e_ = __expf(2.f * x_); \
        AM = 1.f - 2.f * __builtin_amdgcn_rcpf(e_ + 1.f); \
        ssq = fmaf(AM, AM, ssq); }
    TANH_STEP(acc0.x, cgA.x, cbA.x) TANH_STEP(acc0.y, cgA.y, cbA.y)
    TANH_STEP(acc0.z, cgA.z, cbA.z) TANH_STEP(acc0.w, cgA.w, cbA.w)
    TANH_STEP(acc1.x, cgB.x, cbB.x) TANH_STEP(acc1.y, cgB.y, cbB.y)
    TANH_STEP(acc1.z, cgB.z, cbB.z) TANH_STEP(acc1.w, cgB.w, cbB.w)
    ssq = qred16(ssq);
    const float invq = __builtin_amdgcn_rcpf(fmaxf(sqrtf(ssq), 1e-6f));

    const float4 pgA = *(const float4*)(pg + 4 * q);
    const float4 pgB = *(const float4*)(pg + 64 + 4 * q);
    const float4 pbA = *(const float4*)(pb + 4 * q);
    const float4 pbB = *(const float4*)(pb + 64 + 4 * q);

    float aqg = 0.f, aqb = 0.f;
#define QG_STEP(AM, GM, BM_) { \
        float qn_ = AM * invq; \
        AM = qn_ * GM; \
        aqg += AM; \
        aqb = fmaf(qn_, BM_, aqb); }
    QG_STEP(acc0.x, pgA.x, pbA.x) QG_STEP(acc0.y, pgA.y, pbA.y)
    QG_STEP(acc0.z, pgA.z, pbA.z) QG_STEP(acc0.w, pgA.w, pbA.w)
    QG_STEP(acc1.x, pgB.x, pbB.x) QG_STEP(acc1.y, pgB.y, pbB.y)
    QG_STEP(acc1.z, pgB.z, pbB.z) QG_STEP(acc1.w, pgB.w, pbB.w)
    aqg = qred16(aqg);
    aqb = qred16(aqb);

    const float sbb = (ws + KTOT * D + D)[2];
    const float tempc = fminf(fmaxf(temp[0], 0.05f), 2.0f) + 1e-4f;
    const float its = 1.0f / tempc;
    float mups[NP], rsps[NP], simv[NP];
    #pragma unroll
    for (int p = 0; p < NP; ++p) {
        float s_x = (px[p][0].x + px[p][0].y) + (px[p][0].z + px[p][0].w)
                  + (px[p][1].x + px[p][1].y) + (px[p][1].z + px[p][1].w);
        float sxx = 0.f, sqgx = 0.f;
        SQ4(sxx, px[p][0]) SQ4(sxx, px[p][1])
        DOT4(sqgx, acc0, px[p][0]) DOT4(sqgx, acc1, px[p][1])
        s_x = qred16(s_x); sxx = qred16(sxx); sqgx = qred16(sqgx);
        const float mup = s_x * (1.f / D);
        const float varp = sxx * (1.f / D) - mup * mup;
        const float rsp = __builtin_amdgcn_rsqf(varp + LN_EPS);
        float sz2 = 0.f, szb = 0.f;
#define ZSTEP(XM, GM, BM_) { \
        float z_ = (XM - mup) * GM; \
        sz2 = fmaf(z_, z_, sz2); \
        szb = fmaf(z_, BM_, szb); }
        ZSTEP(px[p][0].x, pgA.x, pbA.x) ZSTEP(px[p][0].y, pgA.y, pbA.y)
        ZSTEP(px[p][0].z, pgA.z, pbA.z) ZSTEP(px[p][0].w, pgA.w, pbA.w)
        ZSTEP(px[p][1].x, pgB.x, pbB.x) ZSTEP(px[p][1].y, pgB.y, pbB.y)
        ZSTEP(px[p][1].z, pgB.z, pbB.z) ZSTEP(px[p][1].w, pgB.w, pbB.w)
        sz2 = qred16(sz2); szb = qred16(szb);
        const float dot = fmaf(rsp, sqgx - mup * aqg, aqb);
        float nrm2 = fmaf(rsp * rsp, sz2, fmaf(2.f * rsp, szb, sbb));
        nrm2 = fmaxf(nrm2, 0.f);
        const float inv = __builtin_amdgcn_rcpf(fmaxf(sqrtf(nrm2), 1e-6f));
        mups[p] = mup;
        rsps[p] = rsp;
        simv[p] = clipf(dot * inv, -30.f, 30.f) * its;
    }

    float mx = fmaxf(fmaxf(fmaxf(simv[0], simv[1]), fmaxf(simv[2], simv[3])), simv[4]);
    float wp[NP];
    float Z = 0.f;
    #pragma unroll
    for (int p = 0; p < NP; ++p) { float ev = __expf(simv[p] - mx); wp[p] = ev; Z += ev; }
    const float iZ = 1.f / Z;
    float a0 = 0.f, a1 = 0.f;
    #pragma unroll
    for (int p = 0; p < NP; ++p) {
        float at = wp[p] * iZ;
        a0 += at;
        float w = at * rsps[p];
        a1 = fmaf(w, mups[p], a1);
        wp[p] = w;
    }

    float4 S0 = make_float4(0.f, 0.f, 0.f, 0.f);
    float4 S1 = make_float4(0.f, 0.f, 0.f, 0.f);
    #pragma unroll
    for (int p = 0; p < NP; ++p) {
        AXPY4(S0, wp[p], px[p][0]);
        AXPY4(S1, wp[p], px[p][1]);
    }

    const float4 gc0 = *(const float4*)(gw + D + 4 * q);
    const float4 gc1 = *(const float4*)(gw + D + 64 + 4 * q);
#define CAND_STEP(SM, GM, BM_, GWm) { \
        SM = clipf(fmaf(GM, SM - a1, BM_ * a0), -5.f, 5.f); \
        gsum = fmaf(GWm, SM, gsum); }
    CAND_STEP(S0.x, pgA.x, pbA.x, gc0.x) CAND_STEP(S0.y, pgA.y, pbA.y, gc0.y)
    CAND_STEP(S0.z, pgA.z, pbA.z, gc0.z) CAND_STEP(S0.w, pgA.w, pbA.w, gc0.w)
    CAND_STEP(S1.x, pgB.x, pbB.x, gc1.x) CAND_STEP(S1.y, pgB.y, pbB.y, gc1.y)
    CAND_STEP(S1.z, pgB.z, pbB.z, gc1.z) CAND_STEP(S1.w, pgB.w, pbB.w, gc1.w)
    gsum = qred16(gsum);
    const float gpre = gsum + gb[0];
    const float gate = __builtin_amdgcn_rcpf(1.f + __expf(-gpre));

    float su = 0.f, ssu = 0.f;
#define BLEND_STEP(SM, RM) { \
        SM = fmaf(gate, SM - RM, RM); \
        su += SM; \
        ssu = fmaf(SM, SM, ssu); }
    BLEND_STEP(S0.x, rw0.x) BLEND_STEP(S0.y, rw0.y)
    BLEND_STEP(S0.z, rw0.z) BLEND_STEP(S0.w, rw0.w)
    BLEND_STEP(S1.x, rw1.x) BLEND_STEP(S1.y, rw1.y)
    BLEND_STEP(S1.z, rw1.z) BLEND_STEP(S1.w, rw1.w)
    su = qred16(su);
    ssu = qred16(ssu);
    const float muu = su * (1.f / D);
    const float varu = ssu * (1.f / D) - muu * muu;
    const float rsu = __builtin_amdgcn_rsqf(varu + LN_EPS);

    if (active) {
#define OUT_STEP(SM, GM, BM_) clipf(fmaf((SM - muu) * rsu, GM, BM_), -10.f, 10.f)
        float4 o0, o1;
        o0.x = OUT_STEP(S0.x, cgA.x, cbA.x); o0.y = OUT_STEP(S0.y, cgA.y, cbA.y);
        o0.z = OUT_STEP(S0.z, cgA.z, cbA.z); o0.w = OUT_STEP(S0.w, cgA.w, cbA.w);
        o1.x = OUT_STEP(S1.x, cgB.x, cbB.x); o1.y = OUT_STEP(S1.y, cgB.y, cbB.y);
        o1.z = OUT_STEP(S1.z, cgB.z, cbB.z); o1.w = OUT_STEP(S1.w, cgB.w, cbB.w);
        *(float4*)(out + (size_t)b * D + 4 * q) = o0;
        *(float4*)(out + (size_t)b * D + 64 + 4 * q) = o1;
    }
}

extern "C" void kernel_launch(void* const* d_in, const int* in_sizes, int n_in,
                              void* d_out, int out_size, void* d_ws, size_t ws_size,
                              hipStream_t stream) {
    const int*   nids = (const int*)d_in[0];
    const float* ef   = (const float*)d_in[1];
    const float* t    = (const float*)d_in[2];
    const float* raw  = (const float*)d_in[3];
    const float* prot = (const float*)d_in[4];
    const float* pg   = (const float*)d_in[5];
    const float* pb   = (const float*)d_in[6];
    const float* tw   = (const float*)d_in[7];
    const float* tb   = (const float*)d_in[8];
    const float* ew   = (const float*)d_in[9];
    const float* eb   = (const float*)d_in[10];
    const float* qw   = (const float*)d_in[11];
    const float* qb   = (const float*)d_in[12];
    const float* cg   = (const float*)d_in[13];
    const float* cb   = (const float*)d_in[14];
    const float* gw   = (const float*)d_in[15];
    const float* gb   = (const float*)d_in[16];
    const float* temp = (const float*)d_in[17];
    float* ws  = (float*)d_ws;
    float* out = (float*)d_out;
    const int Btot = in_sizes[0];

    hipLaunchKernelGGL(k0_fold, dim3(258), dim3(128), 0, stream,
                       qw, qb, ew, eb, pg, pb, ws);
    hipLaunchKernelGGL(k0b_pack, dim3(64), dim3(64), 0, stream, ws);
    hipLaunchKernelGGL(k_mfma, dim3((Btot + 63) / 64), dim3(256), 0, stream,
                       nids, ef, t, raw, tw, tb, ws, out, Btot);
    hipLaunchKernelGGL(k_epi, dim3((Btot + EPB - 1) / EPB), dim3(256), 0, stream,
                       nids, t, raw, prot, pg, pb, tw, tb, cg, cb, gw, gb, temp, ws, out, Btot);
}

// Round 8
// 142.979 us; speedup vs baseline: 4.5145x; 1.0556x over previous
//
#include <hip/hip_runtime.h>

#define D 128
#define EDIM 64
#define TDIM 64
#define KTOT 256
#define NP 5
#define LN_EPS 1e-4f
#define WSB_OFF 33024   // float offset of bf16 B-fragments in ws

typedef float v4f __attribute__((ext_vector_type(4)));
typedef float f32x4 __attribute__((ext_vector_type(4)));
typedef short bf16x8 __attribute__((ext_vector_type(8)));

__device__ __forceinline__ float clipf(float x, float lo, float hi) {
    return fminf(fmaxf(x, lo), hi);
}

__device__ __forceinline__ unsigned short bf16rne(float x) {
    unsigned int u = __float_as_uint(x);
    unsigned int r = (u + 0x7fffu + ((u >> 16) & 1u)) >> 16;
    return (unsigned short)r;
}
__device__ __forceinline__ float bf16tof(unsigned short h) {
    return __uint_as_float(((unsigned int)h) << 16);
}

// sum across each 16-lane DPP row — pure-VALU DPP reduction.
template <int CTRL>
__device__ __forceinline__ float dpp_addstep(float v) {
    int o = __builtin_amdgcn_update_dpp(0, __float_as_int(v), CTRL, 0xF, 0xF, true);
    return v + __int_as_float(o);
}
__device__ __forceinline__ float qred16(float v) {
    v = dpp_addstep<0xB1>(v);    // quad_perm xor 1
    v = dpp_addstep<0x4E>(v);    // quad_perm xor 2
    v = dpp_addstep<0x124>(v);   // row_ror:4
    v = dpp_addstep<0x128>(v);   // row_ror:8
    return v;
}

// ---------------- K0: fold weights into ws ----------------
// ws layout (floats): Wt[256*128] (k-major), c0[128], cc[3]={sgg,sgb,sbb},
// then at WSB_OFF: bf16x8 B-fragments [kb(8)][nt(8)][s(2)][lane(64)].
__global__ void k0_fold(const float* __restrict__ qw, const float* __restrict__ qb,
                        const float* __restrict__ ew, const float* __restrict__ eb,
                        const float* __restrict__ pg, const float* __restrict__ pb,
                        float* __restrict__ ws) {
    const int d = threadIdx.x;   // 0..127
    const int bk = blockIdx.x;   // 0..257
    float* Wt = ws;
    float* c0 = ws + KTOT * D;
    float* cc = c0 + D;
    if (bk < 128) {
        Wt[bk * D + d] = qw[d * 320 + bk];
    } else if (bk < 192) {
        const int e = bk - 128;
        const float4* qrow = (const float4*)(qw + d * 320 + 128);
        float s = 0.f;
        #pragma unroll
        for (int g = 0; g < 32; ++g) {
            float4 q = qrow[g];
            s = fmaf(q.x, ew[(4 * g + 0) * EDIM + e], s);
            s = fmaf(q.y, ew[(4 * g + 1) * EDIM + e], s);
            s = fmaf(q.z, ew[(4 * g + 2) * EDIM + e], s);
            s = fmaf(q.w, ew[(4 * g + 3) * EDIM + e], s);
        }
        Wt[bk * D + d] = s;
    } else if (bk < 256) {
        Wt[bk * D + d] = qw[d * 320 + 256 + (bk - 192)];
    } else if (bk == 256) {
        const float4* qrow = (const float4*)(qw + d * 320 + 128);
        const float4* eb4 = (const float4*)eb;
        float s = qb[d];
        #pragma unroll
        for (int g = 0; g < 32; ++g) {
            float4 q = qrow[g], e4 = eb4[g];
            s = fmaf(q.x, e4.x, s); s = fmaf(q.y, e4.y, s);
            s = fmaf(q.z, e4.z, s); s = fmaf(q.w, e4.w, s);
        }
        c0[d] = s;
    } else {
        if (d == 0) { float s = 0.f; for (int i = 0; i < D; ++i) s = fmaf(pg[i], pg[i], s); cc[0] = s; }
        if (d == 1) { float s = 0.f; for (int i = 0; i < D; ++i) s = fmaf(pg[i], pb[i], s); cc[1] = s; }
        if (d == 2) { float s = 0.f; for (int i = 0; i < D; ++i) s = fmaf(pb[i], pb[i], s); cc[2] = s; }
    }
}

// ---------------- K0b: pack Wt into split-bf16 MFMA B-fragments ----------------
// B[k][col]: lane l holds k = kb*32 + (l>>4)*8 + j, col = nt*16 + (l&15).
__global__ void k0b_pack(float* __restrict__ ws) {
    const int kb = blockIdx.x >> 3;
    const int nt = blockIdx.x & 7;
    const int l = threadIdx.x;    // 0..63
    const float* Wt = ws;
    const int col = nt * 16 + (l & 15);
    const int kbase = kb * 32 + (l >> 4) * 8;
    bf16x8 hi, lo;
    #pragma unroll
    for (int j = 0; j < 8; ++j) {
        float x = Wt[(kbase + j) * D + col];
        unsigned short h = bf16rne(x);
        hi[j] = (short)h;
        lo[j] = (short)bf16rne(x - bf16tof(h));
    }
    bf16x8* outp = (bf16x8*)(ws + WSB_OFF);
    outp[((kb * 8 + nt) * 2 + 0) * 64 + l] = hi;
    outp[((kb * 8 + nt) * 2 + 1) * 64 + l] = lo;
}

// ---------------- K_fused: MFMA GEMM + full epilogue, no q_pre round-trip ----
// Per wave: one 16-elem m-tile.
// A-side: element = lane&15, k = kb*32 + (lane>>4)*8 + j  (matches k0b pack).
// C-side: element = (lane>>4)*4 + r, dims = {j*16 + (lane&15) : j=0..7} [m89].
__global__ __launch_bounds__(256, 2)
void k_fused(const int* __restrict__ nids, const float* __restrict__ ef,
             const float* __restrict__ tarr, const float* __restrict__ raw_mem,
             const float* __restrict__ protos,
             const float* __restrict__ pg, const float* __restrict__ pb,
             const float* __restrict__ tw, const float* __restrict__ tb,
             const float* __restrict__ cg, const float* __restrict__ cb,
             const float* __restrict__ gw, const float* __restrict__ gb,
             const float* __restrict__ temp, const float* __restrict__ ws,
             float* __restrict__ out, int Btot) {
    const int tid = threadIdx.x;
    const int lane = tid & 63;
    const int wave = tid >> 6;
    const int m0 = blockIdx.x * 64 + wave * 16;
    const int col = lane & 15;
    const int kg = lane >> 4;

    // ================= GEMM phase (A-side) =================
    const int elemA = min(m0 + col, Btot - 1);
    const int nidA = nids[elemA];
    const float* rawpA = raw_mem + (size_t)nidA * D + kg * 8;
    const float* efpA = ef + (size_t)elemA * EDIM + kg * 8;
    const float tvalA = tarr[elemA];
    const bf16x8* wb = (const bf16x8*)(ws + WSB_OFF);

    f32x4 acc[8];
    #pragma unroll
    for (int nt = 0; nt < 8; ++nt) acc[nt] = (f32x4){0.f, 0.f, 0.f, 0.f};

    #pragma unroll 1
    for (int kb = 0; kb < 8; ++kb) {
        float xs[8];
        if (kb < 4) {
            v4f a = *(const v4f*)(rawpA + kb * 32);
            v4f b = *(const v4f*)(rawpA + kb * 32 + 4);
            xs[0] = a[0]; xs[1] = a[1]; xs[2] = a[2]; xs[3] = a[3];
            xs[4] = b[0]; xs[5] = b[1]; xs[6] = b[2]; xs[7] = b[3];
        } else if (kb < 6) {
            v4f a = *(const v4f*)(efpA + (kb - 4) * 32);
            v4f b = *(const v4f*)(efpA + (kb - 4) * 32 + 4);
            xs[0] = a[0]; xs[1] = a[1]; xs[2] = a[2]; xs[3] = a[3];
            xs[4] = b[0]; xs[5] = b[1]; xs[6] = b[2]; xs[7] = b[3];
        } else {
            const int u0 = (kb - 6) * 32 + kg * 8;
            v4f wa = *(const v4f*)(tw + u0);
            v4f wbv = *(const v4f*)(tw + u0 + 4);
            v4f ba = *(const v4f*)(tb + u0);
            v4f bbv = *(const v4f*)(tb + u0 + 4);
            xs[0] = __cosf(fmaf(tvalA, wa[0], ba[0]));
            xs[1] = __cosf(fmaf(tvalA, wa[1], ba[1]));
            xs[2] = __cosf(fmaf(tvalA, wa[2], ba[2]));
            xs[3] = __cosf(fmaf(tvalA, wa[3], ba[3]));
            xs[4] = __cosf(fmaf(tvalA, wbv[0], bbv[0]));
            xs[5] = __cosf(fmaf(tvalA, wbv[1], bbv[1]));
            xs[6] = __cosf(fmaf(tvalA, wbv[2], bbv[2]));
            xs[7] = __cosf(fmaf(tvalA, wbv[3], bbv[3]));
        }
        bf16x8 ahi, alo;
        #pragma unroll
        for (int j = 0; j < 8; ++j) {
            unsigned short h = bf16rne(xs[j]);
            ahi[j] = (short)h;
            alo[j] = (short)bf16rne(xs[j] - bf16tof(h));
        }
        #pragma unroll
        for (int nt = 0; nt < 8; ++nt) {
            bf16x8 bhi = wb[((kb * 8 + nt) * 2 + 0) * 64 + lane];
            bf16x8 blo = wb[((kb * 8 + nt) * 2 + 1) * 64 + lane];
            acc[nt] = __builtin_amdgcn_mfma_f32_16x16x32_bf16(ahi, bhi, acc[nt], 0, 0, 0);
            acc[nt] = __builtin_amdgcn_mfma_f32_16x16x32_bf16(ahi, blo, acc[nt], 0, 0, 0);
            acc[nt] = __builtin_amdgcn_mfma_f32_16x16x32_bf16(alo, bhi, acc[nt], 0, 0, 0);
        }
    }

    // ================= epilogue phase (C-side) =================
    const float* c0 = ws + KTOT * D;
    const float sbb = (ws + KTOT * D + D)[2];
    const float tempc = fminf(fmaxf(temp[0], 0.05f), 2.0f) + 1e-4f;
    const float its = 1.0f / tempc;
    const float gbias = gb[0];

    // per-lane constants at dims d_j = j*16 + col
    float pg8[8], pb8[8], cg8[8], cb8[8], gwr8[8], gwc8[8], c08[8];
    #pragma unroll
    for (int j = 0; j < 8; ++j) {
        const int dd = j * 16 + col;
        pg8[j] = pg[dd]; pb8[j] = pb[dd];
        cg8[j] = cg[dd]; cb8[j] = cb[dd];
        gwr8[j] = gw[dd]; gwc8[j] = gw[D + dd];
        c08[j] = c0[dd];
    }
    // te-gate constants: u = col*4 + j  (16 lanes × 4 = 64 dims)
    float twc[4], tbc[4], gwt[4];
    #pragma unroll
    for (int j = 0; j < 4; ++j) {
        const int u = col * 4 + j;
        twc[j] = tw[u]; tbc[j] = tb[u]; gwt[j] = gw[2 * D + u];
    }

    #pragma unroll
    for (int r = 0; r < 4; ++r) {
        const int erow = m0 + kg * 4 + r;
        const bool act = (erow < Btot);
        const int ebb = act ? erow : Btot - 1;
        const int nid = nids[ebb];
        const float* rawrow = raw_mem + (size_t)nid * D;
        const float* prow = protos + (size_t)nid * (NP * D);
        const float tval = tarr[ebb];

        float qv[8], rawv[8];
        #pragma unroll
        for (int j = 0; j < 8; ++j) {
            qv[j] = acc[j][r] + c08[j];
            rawv[j] = rawrow[j * 16 + col];
        }
        float pxv[NP][8];
        #pragma unroll
        for (int p = 0; p < NP; ++p) {
            #pragma unroll
            for (int j = 0; j < 8; ++j) pxv[p][j] = prow[p * D + j * 16 + col];
        }

        // gate partials: raw share (8 dims) + te share (4 dims), reduced later
        float gsum = 0.f;
        #pragma unroll
        for (int j = 0; j < 8; ++j) gsum = fmaf(gwr8[j], clipf(rawv[j], -100.f, 100.f), gsum);
        #pragma unroll
        for (int j = 0; j < 4; ++j) gsum = fmaf(gwt[j], __cosf(fmaf(tval, twc[j], tbc[j])), gsum);

        // ---- query = tanh(LN(q_pre)) ----
        float sx = 0.f;
        #pragma unroll
        for (int j = 0; j < 8; ++j) sx += qv[j];
        sx = qred16(sx);
        const float mu = sx * (1.f / D);
        float sv = 0.f;
        #pragma unroll
        for (int j = 0; j < 8; ++j) { float a = qv[j] - mu; sv = fmaf(a, a, sv); }
        sv = qred16(sv);
        const float rsq = __builtin_amdgcn_rsqf(sv * (1.f / D) + LN_EPS);

        float ssq = 0.f;
        #pragma unroll
        for (int j = 0; j < 8; ++j) {
            float x = fmaf((qv[j] - mu) * rsq, cg8[j], cb8[j]);
            float e2x = __expf(2.f * x);
            float th = 1.f - 2.f * __builtin_amdgcn_rcpf(e2x + 1.f);
            qv[j] = th;
            ssq = fmaf(th, th, ssq);
        }
        ssq = qred16(ssq);
        const float invq = __builtin_amdgcn_rcpf(fmaxf(sqrtf(ssq), 1e-6f));

        float aqg = 0.f, aqb = 0.f;
        #pragma unroll
        for (int j = 0; j < 8; ++j) {
            float qn = qv[j] * invq;
            float qg = qn * pg8[j];
            aqg += qg;
            aqb = fmaf(qn, pb8[j], aqb);
            qv[j] = qg;    // qv now holds qn*g
        }
        aqg = qred16(aqg);
        aqb = qred16(aqb);

        // ---- per-proto LN stats + cosine sim ----
        float mups[NP], rsps[NP], simv[NP];
        #pragma unroll
        for (int p = 0; p < NP; ++p) {
            float s_x = 0.f, sxx = 0.f, sqgx = 0.f;
            #pragma unroll
            for (int j = 0; j < 8; ++j) {
                float x = pxv[p][j];
                s_x += x;
                sxx = fmaf(x, x, sxx);
                sqgx = fmaf(qv[j], x, sqgx);
            }
            s_x = qred16(s_x); sxx = qred16(sxx); sqgx = qred16(sqgx);
            const float mup = s_x * (1.f / D);
            const float varp = sxx * (1.f / D) - mup * mup;
            const float rsp = __builtin_amdgcn_rsqf(varp + LN_EPS);
            float sz2 = 0.f, szb = 0.f;
            #pragma unroll
            for (int j = 0; j < 8; ++j) {
                float z = (pxv[p][j] - mup) * pg8[j];
                sz2 = fmaf(z, z, sz2);
                szb = fmaf(z, pb8[j], szb);
            }
            sz2 = qred16(sz2); szb = qred16(szb);
            const float dot = fmaf(rsp, sqgx - mup * aqg, aqb);
            float nrm2 = fmaf(rsp * rsp, sz2, fmaf(2.f * rsp, szb, sbb));
            nrm2 = fmaxf(nrm2, 0.f);
            const float inv = __builtin_amdgcn_rcpf(fmaxf(sqrtf(nrm2), 1e-6f));
            mups[p] = mup;
            rsps[p] = rsp;
            simv[p] = clipf(dot * inv, -30.f, 30.f) * its;
        }

        // ---- softmax over 5 ----
        float mx = fmaxf(fmaxf(fmaxf(simv[0], simv[1]), fmaxf(simv[2], simv[3])), simv[4]);
        float wp[NP];
        float Z = 0.f;
        #pragma unroll
        for (int p = 0; p < NP; ++p) { float ev = __expf(simv[p] - mx); wp[p] = ev; Z += ev; }
        const float iZ = 1.f / Z;
        float a0 = 0.f, a1 = 0.f;
        #pragma unroll
        for (int p = 0; p < NP; ++p) {
            float at = wp[p] * iZ;
            a0 += at;
            float w = at * rsps[p];
            a1 = fmaf(w, mups[p], a1);
            wp[p] = w;
        }

        // ---- weighted proto sum, cand, gate ----
        float S8[8];
        #pragma unroll
        for (int j = 0; j < 8; ++j) S8[j] = 0.f;
        #pragma unroll
        for (int p = 0; p < NP; ++p) {
            #pragma unroll
            for (int j = 0; j < 8; ++j) S8[j] = fmaf(wp[p], pxv[p][j], S8[j]);
        }
        float gc = gsum;
        #pragma unroll
        for (int j = 0; j < 8; ++j) {
            float cnd = clipf(fmaf(pg8[j], S8[j] - a1, pb8[j] * a0), -5.f, 5.f);
            gc = fmaf(gwc8[j], cnd, gc);
            S8[j] = cnd;
        }
        gc = qred16(gc);
        const float gpre = gc + gbias;
        const float gate = __builtin_amdgcn_rcpf(1.f + __expf(-gpre));

        // ---- blend, LN, clip, store ----
        float su = 0.f, ssu = 0.f;
        #pragma unroll
        for (int j = 0; j < 8; ++j) {
            float u = fmaf(gate, S8[j] - rawv[j], rawv[j]);
            S8[j] = u;
            su += u;
            ssu = fmaf(u, u, ssu);
        }
        su = qred16(su);
        ssu = qred16(ssu);
        const float muu = su * (1.f / D);
        const float varu = ssu * (1.f / D) - muu * muu;
        const float rsu = __builtin_amdgcn_rsqf(varu + LN_EPS);

        if (act) {
            float* orow = out + (size_t)erow * D;
            #pragma unroll
            for (int j = 0; j < 8; ++j) {
                orow[j * 16 + col] = clipf(fmaf((S8[j] - muu) * rsu, cg8[j], cb8[j]), -10.f, 10.f);
            }
        }
    }
}

extern "C" void kernel_launch(void* const* d_in, const int* in_sizes, int n_in,
                              void* d_out, int out_size, void* d_ws, size_t ws_size,
                              hipStream_t stream) {
    const int*   nids = (const int*)d_in[0];
    const float* ef   = (const float*)d_in[1];
    const float* t    = (const float*)d_in[2];
    const float* raw  = (const float*)d_in[3];
    const float* prot = (const float*)d_in[4];
    const float* pg   = (const float*)d_in[5];
    const float* pb   = (const float*)d_in[6];
    const float* tw   = (const float*)d_in[7];
    const float* tb   = (const float*)d_in[8];
    const float* ew   = (const float*)d_in[9];
    const float* eb   = (const float*)d_in[10];
    const float* qw   = (const float*)d_in[11];
    const float* qb   = (const float*)d_in[12];
    const float* cg   = (const float*)d_in[13];
    const float* cb   = (const float*)d_in[14];
    const float* gw   = (const float*)d_in[15];
    const float* gb   = (const float*)d_in[16];
    const float* temp = (const float*)d_in[17];
    float* ws  = (float*)d_ws;
    float* out = (float*)d_out;
    const int Btot = in_sizes[0];

    hipLaunchKernelGGL(k0_fold, dim3(258), dim3(128), 0, stream,
                       qw, qb, ew, eb, pg, pb, ws);
    hipLaunchKernelGGL(k0b_pack, dim3(64), dim3(64), 0, stream, ws);
    hipLaunchKernelGGL(k_fused, dim3((Btot + 63) / 64), dim3(256), 0, stream,
                       nids, ef, t, raw, prot, pg, pb, tw, tb, cg, cb, gw, gb, temp, ws, out, Btot);
}

// Round 9
// 120.484 us; speedup vs baseline: 5.3573x; 1.1867x over previous
//
#include <hip/hip_runtime.h>

#define D 128
#define EDIM 64
#define TDIM 64
#define KTOT 256
#define NP 5
#define LN_EPS 1e-4f
#define WSB_OFF 33024   // float offset of bf16 B-fragments in ws

typedef float v4f __attribute__((ext_vector_type(4)));
typedef float f32x4 __attribute__((ext_vector_type(4)));
typedef short bf16x8 __attribute__((ext_vector_type(8)));

__device__ __forceinline__ float clipf(float x, float lo, float hi) {
    return fminf(fmaxf(x, lo), hi);
}

__device__ __forceinline__ unsigned short bf16rne(float x) {
    unsigned int u = __float_as_uint(x);
    unsigned int r = (u + 0x7fffu + ((u >> 16) & 1u)) >> 16;
    return (unsigned short)r;
}
__device__ __forceinline__ float bf16tof(unsigned short h) {
    return __uint_as_float(((unsigned int)h) << 16);
}

// sum across each 16-lane DPP row — pure-VALU DPP reduction.
template <int CTRL>
__device__ __forceinline__ float dpp_addstep(float v) {
    int o = __builtin_amdgcn_update_dpp(0, __float_as_int(v), CTRL, 0xF, 0xF, true);
    return v + __int_as_float(o);
}
__device__ __forceinline__ float qred16(float v) {
    v = dpp_addstep<0xB1>(v);    // quad_perm xor 1
    v = dpp_addstep<0x4E>(v);    // quad_perm xor 2
    v = dpp_addstep<0x124>(v);   // row_ror:4
    v = dpp_addstep<0x128>(v);   // row_ror:8
    return v;
}

// ---------------- K0: fold weights into ws ----------------
// ws layout (floats): Wt[256*128] (k-major), c0[128], cc[3]={sgg,sgb,sbb},
// then at WSB_OFF: bf16x8 B-fragments [kb(8)][nt(8)][s(2)][lane(64)].
__global__ void k0_fold(const float* __restrict__ qw, const float* __restrict__ qb,
                        const float* __restrict__ ew, const float* __restrict__ eb,
                        const float* __restrict__ pg, const float* __restrict__ pb,
                        float* __restrict__ ws) {
    const int d = threadIdx.x;   // 0..127
    const int bk = blockIdx.x;   // 0..257
    float* Wt = ws;
    float* c0 = ws + KTOT * D;
    float* cc = c0 + D;
    if (bk < 128) {
        Wt[bk * D + d] = qw[d * 320 + bk];
    } else if (bk < 192) {
        const int e = bk - 128;
        const float4* qrow = (const float4*)(qw + d * 320 + 128);
        float s = 0.f;
        #pragma unroll
        for (int g = 0; g < 32; ++g) {
            float4 q = qrow[g];
            s = fmaf(q.x, ew[(4 * g + 0) * EDIM + e], s);
            s = fmaf(q.y, ew[(4 * g + 1) * EDIM + e], s);
            s = fmaf(q.z, ew[(4 * g + 2) * EDIM + e], s);
            s = fmaf(q.w, ew[(4 * g + 3) * EDIM + e], s);
        }
        Wt[bk * D + d] = s;
    } else if (bk < 256) {
        Wt[bk * D + d] = qw[d * 320 + 256 + (bk - 192)];
    } else if (bk == 256) {
        const float4* qrow = (const float4*)(qw + d * 320 + 128);
        const float4* eb4 = (const float4*)eb;
        float s = qb[d];
        #pragma unroll
        for (int g = 0; g < 32; ++g) {
            float4 q = qrow[g], e4 = eb4[g];
            s = fmaf(q.x, e4.x, s); s = fmaf(q.y, e4.y, s);
            s = fmaf(q.z, e4.z, s); s = fmaf(q.w, e4.w, s);
        }
        c0[d] = s;
    } else {
        if (d == 0) { float s = 0.f; for (int i = 0; i < D; ++i) s = fmaf(pg[i], pg[i], s); cc[0] = s; }
        if (d == 1) { float s = 0.f; for (int i = 0; i < D; ++i) s = fmaf(pg[i], pb[i], s); cc[1] = s; }
        if (d == 2) { float s = 0.f; for (int i = 0; i < D; ++i) s = fmaf(pb[i], pb[i], s); cc[2] = s; }
    }
}

// ---------------- K0b: pack Wt into split-bf16 MFMA B-fragments ----------------
// B[k][col]: lane l holds k = kb*32 + (l>>4)*8 + j, col = nt*16 + (l&15).
__global__ void k0b_pack(float* __restrict__ ws) {
    const int kb = blockIdx.x >> 3;
    const int nt = blockIdx.x & 7;
    const int l = threadIdx.x;    // 0..63
    const float* Wt = ws;
    const int col = nt * 16 + (l & 15);
    const int kbase = kb * 32 + (l >> 4) * 8;
    bf16x8 hi, lo;
    #pragma unroll
    for (int j = 0; j < 8; ++j) {
        float x = Wt[(kbase + j) * D + col];
        unsigned short h = bf16rne(x);
        hi[j] = (short)h;
        lo[j] = (short)bf16rne(x - bf16tof(h));
    }
    bf16x8* outp = (bf16x8*)(ws + WSB_OFF);
    outp[((kb * 8 + nt) * 2 + 0) * 64 + l] = hi;
    outp[((kb * 8 + nt) * 2 + 1) * 64 + l] = lo;
}

// ---------------- K_fused: MFMA GEMM (B via shared LDS tile) + full epilogue ----
// Per wave: one 16-elem m-tile.
// A-side: element = lane&15, k = kb*32 + (lane>>4)*8 + j  (matches k0b pack).
// C-side: element = (lane>>4)*4 + r, dims = {j*16 + (lane&15) : j=0..7} [m89].
__global__ __launch_bounds__(256, 3)
void k_fused(const int* __restrict__ nids, const float* __restrict__ ef,
             const float* __restrict__ tarr, const float* __restrict__ raw_mem,
             const float* __restrict__ protos,
             const float* __restrict__ pg, const float* __restrict__ pb,
             const float* __restrict__ tw, const float* __restrict__ tb,
             const float* __restrict__ cg, const float* __restrict__ cb,
             const float* __restrict__ gw, const float* __restrict__ gb,
             const float* __restrict__ temp, const float* __restrict__ ws,
             float* __restrict__ out, int Btot) {
    __shared__ bf16x8 Bs[1024];   // 16 KB: [i = nt*2+s][lane] per current kb
    __shared__ float cst[960];    // gwr[128] gwc[128] tw[64] tb[64] gwt[64] + pad

    const int tid = threadIdx.x;
    const int lane = tid & 63;
    const int wave = tid >> 6;
    const int m0 = blockIdx.x * 64 + wave * 16;
    const int col = lane & 15;
    const int kg = lane >> 4;

    // ---- stage small const table (pg/pb/cg/cb stay in regs; rest in LDS) ----
    if (tid < 128) {
        cst[tid] = gw[tid];              // gwr
        cst[128 + tid] = gw[128 + tid];  // gwc
    } else {
        const int u = tid - 128;
        if (u < 64) { cst[256 + u] = tw[u]; cst[320 + u] = tb[u]; }
        else        { cst[384 + u - 64] = gw[256 + u - 64]; }
    }

    // ================= GEMM phase (A-side) =================
    const int elemA = min(m0 + col, Btot - 1);
    const int nidA = nids[elemA];
    const float* rawpA = raw_mem + (size_t)nidA * D + kg * 8;
    const float* efpA = ef + (size_t)elemA * EDIM + kg * 8;
    const float tvalA = tarr[elemA];
    const bf16x8* wbg = (const bf16x8*)(ws + WSB_OFF);

    f32x4 acc[8];
    #pragma unroll
    for (int nt = 0; nt < 8; ++nt) acc[nt] = (f32x4){0.f, 0.f, 0.f, 0.f};

    // prefetch kb=0: B-stage regs (per-instr layout i*256+tid) + A values
    bf16x8 s0 = wbg[tid], s1 = wbg[256 + tid], s2 = wbg[512 + tid], s3 = wbg[768 + tid];
    v4f xa0 = *(const v4f*)rawpA;
    v4f xa1 = *(const v4f*)(rawpA + 4);

    #pragma unroll 1
    for (int kb = 0; kb < 8; ++kb) {
        __syncthreads();   // previous compute done; Bs free
        Bs[tid] = s0; Bs[256 + tid] = s1; Bs[512 + tid] = s2; Bs[768 + tid] = s3;
        __syncthreads();   // Bs ready
        // ---- prefetch kb+1 (latency hides under MFMA below) ----
        v4f xn0 = xa0, xn1 = xa1;
        if (kb < 7) {
            const int kn = kb + 1;
            const bf16x8* wn = wbg + kn * 1024;
            s0 = wn[tid]; s1 = wn[256 + tid]; s2 = wn[512 + tid]; s3 = wn[768 + tid];
            if (kn < 4) {
                xn0 = *(const v4f*)(rawpA + kn * 32);
                xn1 = *(const v4f*)(rawpA + kn * 32 + 4);
            } else if (kn < 6) {
                xn0 = *(const v4f*)(efpA + (kn - 4) * 32);
                xn1 = *(const v4f*)(efpA + (kn - 4) * 32 + 4);
            } else {
                const int u0 = (kn - 6) * 32 + kg * 8;
                v4f wa = *(const v4f*)(tw + u0);
                v4f wb2 = *(const v4f*)(tw + u0 + 4);
                v4f ba = *(const v4f*)(tb + u0);
                v4f bb2 = *(const v4f*)(tb + u0 + 4);
                #pragma unroll
                for (int j = 0; j < 4; ++j) xn0[j] = __cosf(fmaf(tvalA, wa[j], ba[j]));
                #pragma unroll
                for (int j = 0; j < 4; ++j) xn1[j] = __cosf(fmaf(tvalA, wb2[j], bb2[j]));
            }
        }
        // ---- split current A into hi/lo bf16 fragments ----
        bf16x8 ahi, alo;
        #pragma unroll
        for (int j = 0; j < 4; ++j) {
            unsigned short h = bf16rne(xa0[j]);
            ahi[j] = (short)h;
            alo[j] = (short)bf16rne(xa0[j] - bf16tof(h));
        }
        #pragma unroll
        for (int j = 0; j < 4; ++j) {
            unsigned short h = bf16rne(xa1[j]);
            ahi[4 + j] = (short)h;
            alo[4 + j] = (short)bf16rne(xa1[j] - bf16tof(h));
        }
        // ---- 8 n-tiles × 3 split MFMAs, B from LDS ----
        #pragma unroll
        for (int nt = 0; nt < 8; ++nt) {
            bf16x8 bhi = Bs[(nt * 2 + 0) * 64 + lane];
            bf16x8 blo = Bs[(nt * 2 + 1) * 64 + lane];
            acc[nt] = __builtin_amdgcn_mfma_f32_16x16x32_bf16(ahi, bhi, acc[nt], 0, 0, 0);
            acc[nt] = __builtin_amdgcn_mfma_f32_16x16x32_bf16(ahi, blo, acc[nt], 0, 0, 0);
            acc[nt] = __builtin_amdgcn_mfma_f32_16x16x32_bf16(alo, bhi, acc[nt], 0, 0, 0);
        }
        xa0 = xn0; xa1 = xn1;
    }

    // ================= epilogue phase (C-side) =================
    // fold c0 into acc once
    {
        const float* c0 = ws + KTOT * D;
        #pragma unroll
        for (int j = 0; j < 8; ++j) {
            const float cv = c0[j * 16 + col];
            acc[j][0] += cv; acc[j][1] += cv; acc[j][2] += cv; acc[j][3] += cv;
        }
    }
    const float sbb = (ws + KTOT * D + D)[2];
    const float tempc = fminf(fmaxf(temp[0], 0.05f), 2.0f) + 1e-4f;
    const float its = 1.0f / tempc;
    const float gbias = gb[0];

    // hot per-dim constants in regs
    float pg8[8], pb8[8], cg8[8], cb8[8];
    #pragma unroll
    for (int j = 0; j < 8; ++j) {
        const int dd = j * 16 + col;
        pg8[j] = pg[dd]; pb8[j] = pb[dd];
        cg8[j] = cg[dd]; cb8[j] = cb[dd];
    }

    #pragma unroll
    for (int r = 0; r < 4; ++r) {
        const int erow = m0 + kg * 4 + r;
        const bool act = (erow < Btot);
        const int ebb = act ? erow : Btot - 1;
        const int nid = nids[ebb];
        const float* rawrow = raw_mem + (size_t)nid * D;
        const float* prow = protos + (size_t)nid * (NP * D);
        const float tval = tarr[ebb];

        float qv[8], rawv[8];
        #pragma unroll
        for (int j = 0; j < 8; ++j) {
            qv[j] = acc[j][r];
            rawv[j] = rawrow[j * 16 + col];
        }
        float pxv[NP][8];
        #pragma unroll
        for (int p = 0; p < NP; ++p) {
            #pragma unroll
            for (int j = 0; j < 8; ++j) pxv[p][j] = prow[p * D + j * 16 + col];
        }

        // gate partials: raw share (8 dims) + te share (4 dims)
        float gsum = 0.f;
        #pragma unroll
        for (int j = 0; j < 8; ++j)
            gsum = fmaf(cst[j * 16 + col], clipf(rawv[j], -100.f, 100.f), gsum);
        #pragma unroll
        for (int j = 0; j < 4; ++j) {
            const int u = col * 4 + j;
            gsum = fmaf(cst[384 + u], __cosf(fmaf(tval, cst[256 + u], cst[320 + u])), gsum);
        }

        // ---- query = tanh(LN(q_pre)) ----
        float sx = 0.f;
        #pragma unroll
        for (int j = 0; j < 8; ++j) sx += qv[j];
        sx = qred16(sx);
        const float mu = sx * (1.f / D);
        float sv = 0.f;
        #pragma unroll
        for (int j = 0; j < 8; ++j) { float a = qv[j] - mu; sv = fmaf(a, a, sv); }
        sv = qred16(sv);
        const float rsq = __builtin_amdgcn_rsqf(sv * (1.f / D) + LN_EPS);

        float ssq = 0.f;
        #pragma unroll
        for (int j = 0; j < 8; ++j) {
            float x = fmaf((qv[j] - mu) * rsq, cg8[j], cb8[j]);
            float e2x = __expf(2.f * x);
            float th = 1.f - 2.f * __builtin_amdgcn_rcpf(e2x + 1.f);
            qv[j] = th;
            ssq = fmaf(th, th, ssq);
        }
        ssq = qred16(ssq);
        const float invq = __builtin_amdgcn_rcpf(fmaxf(sqrtf(ssq), 1e-6f));

        float aqg = 0.f, aqb = 0.f;
        #pragma unroll
        for (int j = 0; j < 8; ++j) {
            float qn = qv[j] * invq;
            float qg = qn * pg8[j];
            aqg += qg;
            aqb = fmaf(qn, pb8[j], aqb);
            qv[j] = qg;    // qv now holds qn*g
        }
        aqg = qred16(aqg);
        aqb = qred16(aqb);

        // ---- per-proto LN stats + cosine sim ----
        float mups[NP], rsps[NP], simv[NP];
        #pragma unroll
        for (int p = 0; p < NP; ++p) {
            float s_x = 0.f, sxx = 0.f, sqgx = 0.f;
            #pragma unroll
            for (int j = 0; j < 8; ++j) {
                float x = pxv[p][j];
                s_x += x;
                sxx = fmaf(x, x, sxx);
                sqgx = fmaf(qv[j], x, sqgx);
            }
            s_x = qred16(s_x); sxx = qred16(sxx); sqgx = qred16(sqgx);
            const float mup = s_x * (1.f / D);
            const float varp = sxx * (1.f / D) - mup * mup;
            const float rsp = __builtin_amdgcn_rsqf(varp + LN_EPS);
            float sz2 = 0.f, szb = 0.f;
            #pragma unroll
            for (int j = 0; j < 8; ++j) {
                float z = (pxv[p][j] - mup) * pg8[j];
                sz2 = fmaf(z, z, sz2);
                szb = fmaf(z, pb8[j], szb);
            }
            sz2 = qred16(sz2); szb = qred16(szb);
            const float dot = fmaf(rsp, sqgx - mup * aqg, aqb);
            float nrm2 = fmaf(rsp * rsp, sz2, fmaf(2.f * rsp, szb, sbb));
            nrm2 = fmaxf(nrm2, 0.f);
            const float inv = __builtin_amdgcn_rcpf(fmaxf(sqrtf(nrm2), 1e-6f));
            mups[p] = mup;
            rsps[p] = rsp;
            simv[p] = clipf(dot * inv, -30.f, 30.f) * its;
        }

        // ---- softmax over 5 ----
        float mx = fmaxf(fmaxf(fmaxf(simv[0], simv[1]), fmaxf(simv[2], simv[3])), simv[4]);
        float wp[NP];
        float Z = 0.f;
        #pragma unroll
        for (int p = 0; p < NP; ++p) { float ev = __expf(simv[p] - mx); wp[p] = ev; Z += ev; }
        const float iZ = 1.f / Z;
        float a0 = 0.f, a1 = 0.f;
        #pragma unroll
        for (int p = 0; p < NP; ++p) {
            float at = wp[p] * iZ;
            a0 += at;
            float w = at * rsps[p];
            a1 = fmaf(w, mups[p], a1);
            wp[p] = w;
        }

        // ---- weighted proto sum, cand, gate ----
        float S8[8];
        #pragma unroll
        for (int j = 0; j < 8; ++j) S8[j] = 0.f;
        #pragma unroll
        for (int p = 0; p < NP; ++p) {
            #pragma unroll
            for (int j = 0; j < 8; ++j) S8[j] = fmaf(wp[p], pxv[p][j], S8[j]);
        }
        float gc = gsum;
        #pragma unroll
        for (int j = 0; j < 8; ++j) {
            float cnd = clipf(fmaf(pg8[j], S8[j] - a1, pb8[j] * a0), -5.f, 5.f);
            gc = fmaf(cst[128 + j * 16 + col], cnd, gc);
            S8[j] = cnd;
        }
        gc = qred16(gc);
        const float gpre = gc + gbias;
        const float gate = __builtin_amdgcn_rcpf(1.f + __expf(-gpre));

        // ---- blend, LN, clip, store ----
        float su = 0.f, ssu = 0.f;
        #pragma unroll
        for (int j = 0; j < 8; ++j) {
            float u = fmaf(gate, S8[j] - rawv[j], rawv[j]);
            S8[j] = u;
            su += u;
            ssu = fmaf(u, u, ssu);
        }
        su = qred16(su);
        ssu = qred16(ssu);
        const float muu = su * (1.f / D);
        const float varu = ssu * (1.f / D) - muu * muu;
        const float rsu = __builtin_amdgcn_rsqf(varu + LN_EPS);

        if (act) {
            float* orow = out + (size_t)erow * D;
            #pragma unroll
            for (int j = 0; j < 8; ++j) {
                orow[j * 16 + col] = clipf(fmaf((S8[j] - muu) * rsu, cg8[j], cb8[j]), -10.f, 10.f);
            }
        }
    }
}

extern "C" void kernel_launch(void* const* d_in, const int* in_sizes, int n_in,
                              void* d_out, int out_size, void* d_ws, size_t ws_size,
                              hipStream_t stream) {
    const int*   nids = (const int*)d_in[0];
    const float* ef   = (const float*)d_in[1];
    const float* t    = (const float*)d_in[2];
    const float* raw  = (const float*)d_in[3];
    const float* prot = (const float*)d_in[4];
    const float* pg   = (const float*)d_in[5];
    const float* pb   = (const float*)d_in[6];
    const float* tw   = (const float*)d_in[7];
    const float* tb   = (const float*)d_in[8];
    const float* ew   = (const float*)d_in[9];
    const float* eb   = (const float*)d_in[10];
    const float* qw   = (const float*)d_in[11];
    const float* qb   = (const float*)d_in[12];
    const float* cg   = (const float*)d_in[13];
    const float* cb   = (const float*)d_in[14];
    const float* gw   = (const float*)d_in[15];
    const float* gb   = (const float*)d_in[16];
    const float* temp = (const float*)d_in[17];
    float* ws  = (float*)d_ws;
    float* out = (float*)d_out;
    const int Btot = in_sizes[0];

    hipLaunchKernelGGL(k0_fold, dim3(258), dim3(128), 0, stream,
                       qw, qb, ew, eb, pg, pb, ws);
    hipLaunchKernelGGL(k0b_pack, dim3(64), dim3(64), 0, stream, ws);
    hipLaunchKernelGGL(k_fused, dim3((Btot + 63) / 64), dim3(256), 0, stream,
                       nids, ef, t, raw, prot, pg, pb, tw, tb, cg, cb, gw, gb, temp, ws, out, Btot);
}